// Round 3
// baseline (926.580 us; speedup 1.0000x reference)
//
#include <hip/hip_runtime.h>
#include <stdint.h>
#include <stddef.h>

typedef _Float16 f16;
typedef _Float16 f16x8 __attribute__((ext_vector_type(8)));
typedef _Float16 f16x4 __attribute__((ext_vector_type(4)));
typedef float    f32x4 __attribute__((ext_vector_type(4)));

#define AS1 __attribute__((address_space(1)))
#define AS3 __attribute__((address_space(3)))

__device__ __forceinline__ void gl_lds16(const f16* g, f16* l) {
  // async global->LDS, 16B per lane; LDS dest is uniform base + lane*16
  __builtin_amdgcn_global_load_lds((const AS1 uint32_t*)g, (AS3 uint32_t*)l, 16, 0, 0);
}

// Problem constants: B=32, H=W=56, C=512, nh=8, hd=64, ws=7, S=49, G=64
// tokens/batch = 3136, M_total = 100352

// ---------------------------------------------------------------------------
// k_prep: fp32->fp16 conversions + RoPE table (49 x 32 float2 cos/sin)
//   (byte-identical to the measured 882us baseline)
// ---------------------------------------------------------------------------
__global__ __launch_bounds__(256) void k_prep(
    const float* __restrict__ x, const float* __restrict__ wqkv,
    const float* __restrict__ wproj,
    f16* __restrict__ x16, f16* __restrict__ wqkv16, f16* __restrict__ wproj16,
    float2* __restrict__ tab)
{
  const int XB = 25088, WQ = 384, WP = 128;  // blocks per region (8 elems/thread)
  int b = blockIdx.x, t = threadIdx.x;
  const float* src; f16* dst; long i0;
  if (b < XB)            { src = x;     dst = x16;     i0 = ((long)b*256 + t)*8; }
  else if (b < XB+WQ)    { src = wqkv;  dst = wqkv16;  i0 = ((long)(b-XB)*256 + t)*8; }
  else if (b < XB+WQ+WP) { src = wproj; dst = wproj16; i0 = ((long)(b-XB-WQ)*256 + t)*8; }
  else {
    int id = (b - XB - WQ - WP)*256 + t;
    if (id < 49*32) {
      int s = id >> 5, i = id & 31, j = i >> 1;
      float freq = expf(-(float)(4*j)*(1.0f/64.0f)*9.210340372f); // 10000^(-4j/64)
      float pos = (i & 1) ? (float)(s/7) : (float)(s%7);          // odd=y, even=x
      float a = pos * freq;
      tab[id] = make_float2(cosf(a), sinf(a));
    }
    return;
  }
  const float4* s4 = (const float4*)(src + i0);
  float4 v0 = s4[0], v1 = s4[1];
  f16x8 h = { (f16)v0.x,(f16)v0.y,(f16)v0.z,(f16)v0.w,
              (f16)v1.x,(f16)v1.y,(f16)v1.z,(f16)v1.w };
  *(f16x8*)(dst + i0) = h;
}

// ---------------------------------------------------------------------------
// GEMM core (shared by k_qkv / k_proj): BK=64, 128x128 tile, XOR-swizzled LDS,
// DOUBLE-BUFFERED 2-phase pipeline: stage(kt+1) is issued before the
// MFMA work on kt; one syncthreads (vmcnt drain) per K-step instead of two.
// Staging addresses hoisted: 4 per-lane base pointers; per-kt delta is a
// 128-byte literal that folds into the instruction offset.
// LDS rows are 64 f16 = 128 B; chunk c (16B) of row r stored at c ^ (r&7).
// ---------------------------------------------------------------------------
#define GEMM_PRELUDE()                                                        \
  const int tid = threadIdx.x;                                                \
  const int wave = tid >> 6, ln = tid & 63;                                   \
  const int l15 = ln & 15, quad = ln >> 4;                                    \
  const int wq = wave >> 1, wp = wave & 1;                                    \
  const int srow = ln >> 3, schunk = (ln & 7) ^ srow;                         \
  const f16* pW[4]; const f16* pX[4];                                         \
  _Pragma("unroll")                                                           \
  for (int ii = 0; ii < 4; ++ii) {                                            \
    size_t ro = (size_t)(wave*32 + ii*8 + srow)*512 + schunk*8;               \
    pW[ii] = gW + ro; pX[ii] = gX + ro;                                       \
  }

#define GEMM_STAGE(bsel, kt)                                                  \
  _Pragma("unroll")                                                           \
  for (int ii = 0; ii < 4; ++ii) {                                            \
    gl_lds16(pW[ii] + (kt)*64, &Wt[bsel][(wave*32 + ii*8)*64]);               \
    gl_lds16(pX[ii] + (kt)*64, &Xt[bsel][(wave*32 + ii*8)*64]);               \
  }

#define GEMM_MAIN(bsel)                                                       \
  _Pragma("unroll")                                                           \
  for (int k2 = 0; k2 < 2; ++k2) {                                            \
    f16x8 af[4], bf[4];                                                       \
    int pc = ((k2 * 4 + quad) ^ (l15 & 7)) * 8;                               \
    _Pragma("unroll")                                                         \
    for (int i = 0; i < 4; ++i)                                               \
      af[i] = *(const f16x8*)&Wt[bsel][(wq * 64 + i * 16 + l15) * 64 + pc];   \
    _Pragma("unroll")                                                         \
    for (int j = 0; j < 4; ++j)                                               \
      bf[j] = *(const f16x8*)&Xt[bsel][(wp * 64 + j * 16 + l15) * 64 + pc];   \
    _Pragma("unroll")                                                         \
    for (int i = 0; i < 4; ++i)                                               \
      _Pragma("unroll")                                                       \
      for (int j = 0; j < 4; ++j)                                             \
        acc[i][j] = __builtin_amdgcn_mfma_f32_16x16x32_f16(af[i], bf[j],      \
                                                           acc[i][j], 0, 0, 0);\
  }

// prologue stage; then per kt: issue next-tile loads, compute current tile,
// single vmcnt(0)+barrier. Last iteration: no stage, no barrier (epilogue
// touches no LDS).
#define GEMM_LOOP()                                                           \
  GEMM_STAGE(0, 0);                                                           \
  __syncthreads();                                                            \
  _Pragma("unroll")                                                           \
  for (int kt = 0; kt < 8; ++kt) {                                            \
    if (kt < 7) GEMM_STAGE((kt + 1) & 1, kt + 1);                             \
    GEMM_MAIN(kt & 1);                                                        \
    if (kt < 7) __syncthreads();                                              \
  }

// ---------------------------------------------------------------------------
// k_qkv: C[ch][tok] = sum_k W[ch][k] * X[tok][k]
//   1-D grid, XCD-grouped: all 12 channel-tiles of one token-tile land on the
//   same XCD (bid%8) so the X tile is filled into exactly one L2.
//   epilogue: RoPE on q/k; q,k,v all stored [bgh][s][64] (coalesced f16x4)
// ---------------------------------------------------------------------------
__global__ __launch_bounds__(256) void k_qkv(
    const f16* __restrict__ x16, const f16* __restrict__ w16,
    const float2* __restrict__ tab,
    f16* __restrict__ qb, f16* __restrict__ kb, f16* __restrict__ vb)
{
  __shared__ __align__(16) f16 Wt[2][128*64];
  __shared__ __align__(16) f16 Xt[2][128*64];
  // decode: xcd = bid&7 ; within an XCD, 12 consecutive channel-tiles share bx
  const int bid = blockIdx.x;          // 0..9407
  const int xcd = bid & 7;
  const int jj  = bid >> 3;            // 0..1175
  const int qq  = jj / 12;             // 0..97
  const int by  = jj - qq*12;          // channel tile 0..11 (0-3 q, 4-7 k, 8-11 v)
  const int bx  = xcd + qq*8;          // token tile 0..783

  const f16* gW = w16 + (size_t)(by*128)*512;
  const f16* gX = x16 + (size_t)(bx*128)*512;
  GEMM_PRELUDE();

  f32x4 acc[4][4] = {};
  GEMM_LOOP();

  const int t = (by*128) >> 9;   // 0=q,1=k,2=v (uniform per block)
#pragma unroll
  for (int j = 0; j < 4; ++j) {
    int m  = bx*128 + wp*64 + j*16 + l15;   // token (token-order)
    int b  = m / 3136;
    int nn = m - b*3136;
    int hh = nn / 56, ww = nn - hh*56;
    int gh = hh / 7,  p  = hh - gh*7;
    int gw = ww / 7,  qx = ww - gw*7;
    int g  = gh*8 + gw;
    int s  = p*7 + qx;
    int bg = b*64 + g;
#pragma unroll
    for (int i = 0; i < 4; ++i) {
      int c0   = by*128 + wq*64 + i*16 + quad*4;  // global channel of reg 0
      int cin  = c0 & 511;
      int head = cin >> 6;
      int dd   = cin & 63;                        // multiple of 4
      float v0 = acc[i][j][0], v1 = acc[i][j][1], v2 = acc[i][j][2], v3 = acc[i][j][3];
      f16x4 h4;
      if (t < 2) {
        float2 t0 = tab[s*32 + (dd >> 1)];
        float2 t1 = tab[s*32 + (dd >> 1) + 1];
        h4[0] = (f16)(v0*t0.x - v1*t0.y);
        h4[1] = (f16)(v0*t0.y + v1*t0.x);
        h4[2] = (f16)(v2*t1.x - v3*t1.y);
        h4[3] = (f16)(v2*t1.y + v3*t1.x);
      } else {
        h4[0] = (f16)v0; h4[1] = (f16)v1; h4[2] = (f16)v2; h4[3] = (f16)v3;
      }
      f16* dst = (t == 0 ? qb : (t == 1 ? kb : vb))
               + (size_t)((bg*8 + head)*49 + s)*64 + dd;
      *(f16x4*)dst = h4;
    }
  }
}

// ---------------------------------------------------------------------------
// k_attn: one wave per (b,g,head).  S=49 padded to 64 via clamp+mask.
//   (byte-identical to the measured 882us baseline)
// ---------------------------------------------------------------------------
__global__ __launch_bounds__(64) void k_attn(
    const f16* __restrict__ qb, const f16* __restrict__ kb,
    const f16* __restrict__ vb, f16* __restrict__ ob)
{
  __shared__ __align__(16) f16 Vt[64*64];  // V rows (rows 49..63 = garbage, masked by P=0)
  __shared__ __align__(16) f16 P[64*72];   // unnormalized exp, stride 72 (144B)
  __shared__ float lsum[64];
  const int bid = blockIdx.x;
  const int ln = threadIdx.x, l15 = ln & 15, quad = ln >> 4;
  const f16* q = qb + (size_t)bid*(49*64);
  const f16* k = kb + (size_t)bid*(49*64);
  const f16* v = vb + (size_t)bid*(49*64);

  // stage V: 64 rows x 128 B (reads 15 rows past this window; vb is padded)
#pragma unroll
  for (int i = 0; i < 8; ++i)
    gl_lds16(v + (size_t)(i*8 + (ln>>3))*64 + (ln&7)*8, Vt + i*512);

  // ---- logits = Q K^T
  f32x4 a[4][4] = {};
#pragma unroll
  for (int kt = 0; kt < 2; ++kt) {
    f16x8 qf[4], kf[4];
#pragma unroll
    for (int mt = 0; mt < 4; ++mt) {
      int s = mt*16 + l15; if (s > 48) s = 48;   // clamp pad rows (masked later)
      qf[mt] = *(const f16x8*)(q + s*64 + kt*32 + quad*8);
      kf[mt] = *(const f16x8*)(k + s*64 + kt*32 + quad*8);
    }
#pragma unroll
    for (int mt = 0; mt < 4; ++mt)
#pragma unroll
      for (int nt = 0; nt < 4; ++nt)
        a[mt][nt] = __builtin_amdgcn_mfma_f32_16x16x32_f16(qf[mt], kf[nt], a[mt][nt], 0, 0, 0);
  }

  // ---- softmax rows (row = s_q = mt*16 + quad*4 + r ; col = s_k = nt*16 + l15)
  const float scale = 0.125f;
#pragma unroll
  for (int mt = 0; mt < 4; ++mt) {
    float mx[4] = {-1e30f,-1e30f,-1e30f,-1e30f};
#pragma unroll
    for (int nt = 0; nt < 4; ++nt) {
      int col = nt*16 + l15;
      bool valid = col < 49;
#pragma unroll
      for (int r = 0; r < 4; ++r) {
        float vv = valid ? a[mt][nt][r]*scale : -1e30f;
        a[mt][nt][r] = vv;
        mx[r] = fmaxf(mx[r], vv);
      }
    }
#pragma unroll
    for (int d = 1; d < 16; d <<= 1)
#pragma unroll
      for (int r = 0; r < 4; ++r) mx[r] = fmaxf(mx[r], __shfl_xor(mx[r], d, 64));
    float sm[4] = {0.f,0.f,0.f,0.f};
#pragma unroll
    for (int nt = 0; nt < 4; ++nt)
#pragma unroll
      for (int r = 0; r < 4; ++r) {
        float e = __expf(a[mt][nt][r] - mx[r]);
        a[mt][nt][r] = e;
        sm[r] += e;
      }
#pragma unroll
    for (int d = 1; d < 16; d <<= 1)
#pragma unroll
      for (int r = 0; r < 4; ++r) sm[r] += __shfl_xor(sm[r], d, 64);
#pragma unroll
    for (int nt = 0; nt < 4; ++nt)
#pragma unroll
      for (int r = 0; r < 4; ++r)
        P[(mt*16 + quad*4 + r)*72 + nt*16 + l15] = (f16)a[mt][nt][r];
    if (l15 == 0) {
#pragma unroll
      for (int r = 0; r < 4; ++r) lsum[mt*16 + quad*4 + r] = sm[r];
    }
  }
  __syncthreads();   // also drains the global_load_lds staging of Vt

  // ---- O^T[d][s_q] = sum_s V^T[d][s] * P[s_q][s]   (A=V^T rows, B=P rows)
  f32x4 o[4][4] = {};
#pragma unroll
  for (int kt = 0; kt < 2; ++kt) {
    const int s0 = kt*32 + quad*8;
    f16x8 vf[4], pf[4];
#pragma unroll
    for (int dt = 0; dt < 4; ++dt)
#pragma unroll
      for (int j = 0; j < 8; ++j)
        vf[dt][j] = Vt[(s0 + j)*64 + dt*16 + l15];
#pragma unroll
    for (int st = 0; st < 4; ++st) pf[st] = *(const f16x8*)&P[(st*16 + l15)*72 + s0];
#pragma unroll
    for (int dt = 0; dt < 4; ++dt)
#pragma unroll
      for (int st = 0; st < 4; ++st)
        o[dt][st] = __builtin_amdgcn_mfma_f32_16x16x32_f16(vf[dt], pf[st], o[dt][st], 0, 0, 0);
  }

  const int bg = bid >> 3, head = bid & 7;
#pragma unroll
  for (int st = 0; st < 4; ++st) {
    int sq = st*16 + l15;
    if (sq < 49) {
      float inv = 1.0f / lsum[sq];
#pragma unroll
      for (int dt = 0; dt < 4; ++dt) {
        int d0 = dt*16 + quad*4;
        f16x4 h4 = { (f16)(o[dt][st][0]*inv), (f16)(o[dt][st][1]*inv),
                     (f16)(o[dt][st][2]*inv), (f16)(o[dt][st][3]*inv) };
        *(f16x4*)(ob + (size_t)(bg*49 + sq)*512 + head*64 + d0) = h4;
      }
    }
  }
}

// ---------------------------------------------------------------------------
// k_proj: C[d][row_w] = sum_c Wp[d][c] * A[row_w][c]; +bias; scatter to token
//   same 2-phase pipelined GEMM core + XCD-grouped 1-D grid (4 tiles/XCD group)
// ---------------------------------------------------------------------------
__global__ __launch_bounds__(256) void k_proj(
    const f16* __restrict__ a16, const f16* __restrict__ w16,
    const float* __restrict__ bias, float* __restrict__ out)
{
  __shared__ __align__(16) f16 Wt[2][128*64];
  __shared__ __align__(16) f16 Xt[2][128*64];
  const int bid = blockIdx.x;          // 0..3135
  const int xcd = bid & 7;
  const int jj  = bid >> 3;            // 0..391
  const int qq  = jj >> 2;             // 0..97
  const int by  = jj & 3;              // channel tile 0..3
  const int bx  = xcd + qq*8;          // windowed-row tile 0..783

  const f16* gW = w16 + (size_t)(by*128)*512;
  const f16* gX = a16 + (size_t)(bx*128)*512;
  GEMM_PRELUDE();

  f32x4 acc[4][4] = {};
  GEMM_LOOP();

#pragma unroll
  for (int j = 0; j < 4; ++j) {
    int m  = bx*128 + wp*64 + j*16 + l15;   // windowed row
    int b  = m / 3136;
    int rr = m - b*3136;
    int g  = rr / 49;
    int s  = rr - g*49;
    int gh = g >> 3, gw = g & 7;
    int p  = s / 7,  qx = s - p*7;
    int hh = gh*7 + p, ww = gw*7 + qx;
    size_t tok = (size_t)b*3136 + hh*56 + ww;
#pragma unroll
    for (int i = 0; i < 4; ++i) {
      int d0 = by*128 + wq*64 + i*16 + quad*4;
      float4 bb = *(const float4*)(bias + d0);
      float4 o4 = make_float4(acc[i][j][0]+bb.x, acc[i][j][1]+bb.y,
                              acc[i][j][2]+bb.z, acc[i][j][3]+bb.w);
      *(float4*)(out + tok*512 + d0) = o4;
    }
  }
}

// ---------------------------------------------------------------------------
extern "C" void kernel_launch(void* const* d_in, const int* in_sizes, int n_in,
                              void* d_out, int out_size, void* d_ws, size_t ws_size,
                              hipStream_t stream) {
  const float* x     = (const float*)d_in[0];
  const float* wqkv  = (const float*)d_in[1];
  const float* wproj = (const float*)d_in[2];
  const float* bias  = (const float*)d_in[3];

  char* ws = (char*)d_ws;
  // ws layout (bytes):
  //   [0, 102760448)            x16  -> later aliased by attn_out (fp16)
  //   [102760448, 104333312)    wqkv16
  //   [104333312, 104857600)    wproj16
  //   [104857600, +12544)       rope table (float2[49*32])
  //   [104873984, +102768640)   v [bgh][49][64] fp16 (+8KB pad for Vt staging overrun)
  f16*    x16   = (f16*)(ws);
  f16*    wq16  = (f16*)(ws + 102760448);
  f16*    wp16  = (f16*)(ws + 104333312);
  float2* tab   = (float2*)(ws + 104857600);
  f16*    vbuf  = (f16*)(ws + 104873984);
  f16*    attn16 = (f16*)(ws);              // aliases x16 (dead after k_qkv)

  // q,k live inside d_out (205,520,896 bytes); dead before k_proj writes
  f16* qbuf = (f16*)d_out;
  f16* kbuf = (f16*)((char*)d_out + 102760448);
  float* out = (float*)d_out;

  k_prep<<<dim3(25088 + 384 + 128 + 7), dim3(256), 0, stream>>>(
      x, wqkv, wproj, x16, wq16, wp16, tab);
  k_qkv<<<dim3(9408), dim3(256), 0, stream>>>(x16, wq16, tab, qbuf, kbuf, vbuf);
  k_attn<<<dim3(16384), dim3(64), 0, stream>>>(qbuf, kbuf, vbuf, attn16);
  k_proj<<<dim3(3136), dim3(256), 0, stream>>>(attn16, wp16, bias, out);
}

// Round 4
// 850.848 us; speedup vs baseline: 1.0890x; 1.0890x over previous
//
#include <hip/hip_runtime.h>
#include <stdint.h>
#include <stddef.h>

typedef _Float16 f16;
typedef _Float16 f16x8 __attribute__((ext_vector_type(8)));
typedef _Float16 f16x4 __attribute__((ext_vector_type(4)));
typedef float    f32x4 __attribute__((ext_vector_type(4)));

#define AS1 __attribute__((address_space(1)))
#define AS3 __attribute__((address_space(3)))

__device__ __forceinline__ void gl_lds16(const f16* g, f16* l) {
  // async global->LDS, 16B per lane; LDS dest is uniform base + lane*16
  __builtin_amdgcn_global_load_lds((const AS1 uint32_t*)g, (AS3 uint32_t*)l, 16, 0, 0);
}

// Problem constants: B=32, H=W=56, C=512, nh=8, hd=64, ws=7, S=49, G=64
// tokens/batch = 3136, M_total = 100352

// ---------------------------------------------------------------------------
// k_prep: fp32->fp16 conversions + RoPE table (49 x 32 float2 cos/sin)
//   (byte-identical to the measured 882us baseline)
// ---------------------------------------------------------------------------
__global__ __launch_bounds__(256) void k_prep(
    const float* __restrict__ x, const float* __restrict__ wqkv,
    const float* __restrict__ wproj,
    f16* __restrict__ x16, f16* __restrict__ wqkv16, f16* __restrict__ wproj16,
    float2* __restrict__ tab)
{
  const int XB = 25088, WQ = 384, WP = 128;  // blocks per region (8 elems/thread)
  int b = blockIdx.x, t = threadIdx.x;
  const float* src; f16* dst; long i0;
  if (b < XB)            { src = x;     dst = x16;     i0 = ((long)b*256 + t)*8; }
  else if (b < XB+WQ)    { src = wqkv;  dst = wqkv16;  i0 = ((long)(b-XB)*256 + t)*8; }
  else if (b < XB+WQ+WP) { src = wproj; dst = wproj16; i0 = ((long)(b-XB-WQ)*256 + t)*8; }
  else {
    int id = (b - XB - WQ - WP)*256 + t;
    if (id < 49*32) {
      int s = id >> 5, i = id & 31, j = i >> 1;
      float freq = expf(-(float)(4*j)*(1.0f/64.0f)*9.210340372f); // 10000^(-4j/64)
      float pos = (i & 1) ? (float)(s/7) : (float)(s%7);          // odd=y, even=x
      float a = pos * freq;
      tab[id] = make_float2(cosf(a), sinf(a));
    }
    return;
  }
  const float4* s4 = (const float4*)(src + i0);
  float4 v0 = s4[0], v1 = s4[1];
  f16x8 h = { (f16)v0.x,(f16)v0.y,(f16)v0.z,(f16)v0.w,
              (f16)v1.x,(f16)v1.y,(f16)v1.z,(f16)v1.w };
  *(f16x8*)(dst + i0) = h;
}

// ---------------------------------------------------------------------------
// GEMM core (shared by k_qkv / k_proj): BK=64, 128x128 tile, XOR-swizzled LDS,
// double-buffered with T4 COUNTED vmcnt: the loop never drains vmcnt to 0.
// Before ds-reading buf[kt] we wait vmcnt(8): the 8 newest loads (stage kt+1)
// stay in flight; stage(kt)'s 8 loads (issued a full iteration ago) are done.
// Second raw barrier after the MFMA cluster closes the WAR window (all waves'
// ds-reads of buf[kt] have completed once lgkmcnt==0 there).
// LDS rows are 64 f16 = 128 B; chunk c (16B) of row r stored at c ^ (r&7).
// ---------------------------------------------------------------------------
#define GEMM_PRELUDE()                                                        \
  const int tid = threadIdx.x;                                                \
  const int wave = tid >> 6, ln = tid & 63;                                   \
  const int l15 = ln & 15, quad = ln >> 4;                                    \
  const int wq = wave >> 1, wp = wave & 1;                                    \
  const int srow = ln >> 3, schunk = (ln & 7) ^ srow;                         \
  const f16* pW[4]; const f16* pX[4];                                         \
  _Pragma("unroll")                                                           \
  for (int ii = 0; ii < 4; ++ii) {                                            \
    size_t ro = (size_t)(wave*32 + ii*8 + srow)*512 + schunk*8;               \
    pW[ii] = gW + ro; pX[ii] = gX + ro;                                       \
  }

#define GEMM_STAGE(bsel, kt)                                                  \
  _Pragma("unroll")                                                           \
  for (int ii = 0; ii < 4; ++ii) {                                            \
    gl_lds16(pW[ii] + (kt)*64, &Wt[bsel][(wave*32 + ii*8)*64]);               \
    gl_lds16(pX[ii] + (kt)*64, &Xt[bsel][(wave*32 + ii*8)*64]);               \
  }

#define GEMM_MAIN(bsel)                                                       \
  _Pragma("unroll")                                                           \
  for (int k2 = 0; k2 < 2; ++k2) {                                            \
    f16x8 af[4], bf[4];                                                       \
    int pc = ((k2 * 4 + quad) ^ (l15 & 7)) * 8;                               \
    _Pragma("unroll")                                                         \
    for (int i = 0; i < 4; ++i)                                               \
      af[i] = *(const f16x8*)&Wt[bsel][(wq * 64 + i * 16 + l15) * 64 + pc];   \
    _Pragma("unroll")                                                         \
    for (int j = 0; j < 4; ++j)                                               \
      bf[j] = *(const f16x8*)&Xt[bsel][(wp * 64 + j * 16 + l15) * 64 + pc];   \
    _Pragma("unroll")                                                         \
    for (int i = 0; i < 4; ++i)                                               \
      _Pragma("unroll")                                                       \
      for (int j = 0; j < 4; ++j)                                             \
        acc[i][j] = __builtin_amdgcn_mfma_f32_16x16x32_f16(af[i], bf[j],      \
                                                           acc[i][j], 0, 0, 0);\
  }

// T4 schedule. Per iter kt:
//   stage(kt+1)                      [8 loads issued; <=16 outstanding]
//   s_waitcnt vmcnt(8)               [stage(kt) landed; kt+1 still flying]
//   s_barrier                        [buf[kt] globally ready]
//   ds_reads + MFMA on buf[kt]
//   s_waitcnt lgkmcnt(0); s_barrier  [all waves done reading buf[kt] ->
//                                     safe for iter kt+1 to overwrite buf[kt]]
#define GEMM_LOOP()                                                           \
  GEMM_STAGE(0, 0);                                                           \
  _Pragma("unroll")                                                           \
  for (int kt = 0; kt < 8; ++kt) {                                            \
    if (kt < 7) {                                                             \
      GEMM_STAGE((kt + 1) & 1, kt + 1);                                       \
      asm volatile("s_waitcnt vmcnt(8)" ::: "memory");                        \
    } else {                                                                  \
      asm volatile("s_waitcnt vmcnt(0)" ::: "memory");                        \
    }                                                                         \
    __builtin_amdgcn_sched_barrier(0);                                        \
    __builtin_amdgcn_s_barrier();                                             \
    __builtin_amdgcn_sched_barrier(0);                                        \
    GEMM_MAIN(kt & 1);                                                        \
    if (kt < 7) {                                                             \
      asm volatile("s_waitcnt lgkmcnt(0)" ::: "memory");                      \
      __builtin_amdgcn_sched_barrier(0);                                      \
      __builtin_amdgcn_s_barrier();                                           \
    }                                                                         \
  }

// ---------------------------------------------------------------------------
// k_qkv: C[ch][tok] = sum_k W[ch][k] * X[tok][k]
//   1-D grid, XCD-grouped: all 12 channel-tiles of one token-tile land on the
//   same XCD (bid%8) so the X tile is filled into exactly one L2.
//   epilogue: RoPE on q/k; q,k,v all stored [bgh][s][64] (coalesced f16x4)
// ---------------------------------------------------------------------------
__global__ __launch_bounds__(256) void k_qkv(
    const f16* __restrict__ x16, const f16* __restrict__ w16,
    const float2* __restrict__ tab,
    f16* __restrict__ qb, f16* __restrict__ kb, f16* __restrict__ vb)
{
  __shared__ __align__(16) f16 Wt[2][128*64];
  __shared__ __align__(16) f16 Xt[2][128*64];
  // decode: xcd = bid&7 ; within an XCD, 12 consecutive channel-tiles share bx
  const int bid = blockIdx.x;          // 0..9407
  const int xcd = bid & 7;
  const int jj  = bid >> 3;            // 0..1175
  const int qq  = jj / 12;             // 0..97
  const int by  = jj - qq*12;          // channel tile 0..11 (0-3 q, 4-7 k, 8-11 v)
  const int bx  = xcd + qq*8;          // token tile 0..783

  const f16* gW = w16 + (size_t)(by*128)*512;
  const f16* gX = x16 + (size_t)(bx*128)*512;
  GEMM_PRELUDE();

  f32x4 acc[4][4] = {};
  GEMM_LOOP();

  const int t = (by*128) >> 9;   // 0=q,1=k,2=v (uniform per block)
#pragma unroll
  for (int j = 0; j < 4; ++j) {
    int m  = bx*128 + wp*64 + j*16 + l15;   // token (token-order)
    int b  = m / 3136;
    int nn = m - b*3136;
    int hh = nn / 56, ww = nn - hh*56;
    int gh = hh / 7,  p  = hh - gh*7;
    int gw = ww / 7,  qx = ww - gw*7;
    int g  = gh*8 + gw;
    int s  = p*7 + qx;
    int bg = b*64 + g;
#pragma unroll
    for (int i = 0; i < 4; ++i) {
      int c0   = by*128 + wq*64 + i*16 + quad*4;  // global channel of reg 0
      int cin  = c0 & 511;
      int head = cin >> 6;
      int dd   = cin & 63;                        // multiple of 4
      float v0 = acc[i][j][0], v1 = acc[i][j][1], v2 = acc[i][j][2], v3 = acc[i][j][3];
      f16x4 h4;
      if (t < 2) {
        float2 t0 = tab[s*32 + (dd >> 1)];
        float2 t1 = tab[s*32 + (dd >> 1) + 1];
        h4[0] = (f16)(v0*t0.x - v1*t0.y);
        h4[1] = (f16)(v0*t0.y + v1*t0.x);
        h4[2] = (f16)(v2*t1.x - v3*t1.y);
        h4[3] = (f16)(v2*t1.y + v3*t1.x);
      } else {
        h4[0] = (f16)v0; h4[1] = (f16)v1; h4[2] = (f16)v2; h4[3] = (f16)v3;
      }
      f16* dst = (t == 0 ? qb : (t == 1 ? kb : vb))
               + (size_t)((bg*8 + head)*49 + s)*64 + dd;
      *(f16x4*)dst = h4;
    }
  }
}

// ---------------------------------------------------------------------------
// k_attn: one wave per (b,g,head).  S=49 padded to 64 via clamp+mask.
//   (byte-identical to the measured 882us baseline)
// ---------------------------------------------------------------------------
__global__ __launch_bounds__(64) void k_attn(
    const f16* __restrict__ qb, const f16* __restrict__ kb,
    const f16* __restrict__ vb, f16* __restrict__ ob)
{
  __shared__ __align__(16) f16 Vt[64*64];  // V rows (rows 49..63 = garbage, masked by P=0)
  __shared__ __align__(16) f16 P[64*72];   // unnormalized exp, stride 72 (144B)
  __shared__ float lsum[64];
  const int bid = blockIdx.x;
  const int ln = threadIdx.x, l15 = ln & 15, quad = ln >> 4;
  const f16* q = qb + (size_t)bid*(49*64);
  const f16* k = kb + (size_t)bid*(49*64);
  const f16* v = vb + (size_t)bid*(49*64);

  // stage V: 64 rows x 128 B (reads 15 rows past this window; vb is padded)
#pragma unroll
  for (int i = 0; i < 8; ++i)
    gl_lds16(v + (size_t)(i*8 + (ln>>3))*64 + (ln&7)*8, Vt + i*512);

  // ---- logits = Q K^T
  f32x4 a[4][4] = {};
#pragma unroll
  for (int kt = 0; kt < 2; ++kt) {
    f16x8 qf[4], kf[4];
#pragma unroll
    for (int mt = 0; mt < 4; ++mt) {
      int s = mt*16 + l15; if (s > 48) s = 48;   // clamp pad rows (masked later)
      qf[mt] = *(const f16x8*)(q + s*64 + kt*32 + quad*8);
      kf[mt] = *(const f16x8*)(k + s*64 + kt*32 + quad*8);
    }
#pragma unroll
    for (int mt = 0; mt < 4; ++mt)
#pragma unroll
      for (int nt = 0; nt < 4; ++nt)
        a[mt][nt] = __builtin_amdgcn_mfma_f32_16x16x32_f16(qf[mt], kf[nt], a[mt][nt], 0, 0, 0);
  }

  // ---- softmax rows (row = s_q = mt*16 + quad*4 + r ; col = s_k = nt*16 + l15)
  const float scale = 0.125f;
#pragma unroll
  for (int mt = 0; mt < 4; ++mt) {
    float mx[4] = {-1e30f,-1e30f,-1e30f,-1e30f};
#pragma unroll
    for (int nt = 0; nt < 4; ++nt) {
      int col = nt*16 + l15;
      bool valid = col < 49;
#pragma unroll
      for (int r = 0; r < 4; ++r) {
        float vv = valid ? a[mt][nt][r]*scale : -1e30f;
        a[mt][nt][r] = vv;
        mx[r] = fmaxf(mx[r], vv);
      }
    }
#pragma unroll
    for (int d = 1; d < 16; d <<= 1)
#pragma unroll
      for (int r = 0; r < 4; ++r) mx[r] = fmaxf(mx[r], __shfl_xor(mx[r], d, 64));
    float sm[4] = {0.f,0.f,0.f,0.f};
#pragma unroll
    for (int nt = 0; nt < 4; ++nt)
#pragma unroll
      for (int r = 0; r < 4; ++r) {
        float e = __expf(a[mt][nt][r] - mx[r]);
        a[mt][nt][r] = e;
        sm[r] += e;
      }
#pragma unroll
    for (int d = 1; d < 16; d <<= 1)
#pragma unroll
      for (int r = 0; r < 4; ++r) sm[r] += __shfl_xor(sm[r], d, 64);
#pragma unroll
    for (int nt = 0; nt < 4; ++nt)
#pragma unroll
      for (int r = 0; r < 4; ++r)
        P[(mt*16 + quad*4 + r)*72 + nt*16 + l15] = (f16)a[mt][nt][r];
    if (l15 == 0) {
#pragma unroll
      for (int r = 0; r < 4; ++r) lsum[mt*16 + quad*4 + r] = sm[r];
    }
  }
  __syncthreads();   // also drains the global_load_lds staging of Vt

  // ---- O^T[d][s_q] = sum_s V^T[d][s] * P[s_q][s]   (A=V^T rows, B=P rows)
  f32x4 o[4][4] = {};
#pragma unroll
  for (int kt = 0; kt < 2; ++kt) {
    const int s0 = kt*32 + quad*8;
    f16x8 vf[4], pf[4];
#pragma unroll
    for (int dt = 0; dt < 4; ++dt)
#pragma unroll
      for (int j = 0; j < 8; ++j)
        vf[dt][j] = Vt[(s0 + j)*64 + dt*16 + l15];
#pragma unroll
    for (int st = 0; st < 4; ++st) pf[st] = *(const f16x8*)&P[(st*16 + l15)*72 + s0];
#pragma unroll
    for (int dt = 0; dt < 4; ++dt)
#pragma unroll
      for (int st = 0; st < 4; ++st)
        o[dt][st] = __builtin_amdgcn_mfma_f32_16x16x32_f16(vf[dt], pf[st], o[dt][st], 0, 0, 0);
  }

  const int bg = bid >> 3, head = bid & 7;
#pragma unroll
  for (int st = 0; st < 4; ++st) {
    int sq = st*16 + l15;
    if (sq < 49) {
      float inv = 1.0f / lsum[sq];
#pragma unroll
      for (int dt = 0; dt < 4; ++dt) {
        int d0 = dt*16 + quad*4;
        f16x4 h4 = { (f16)(o[dt][st][0]*inv), (f16)(o[dt][st][1]*inv),
                     (f16)(o[dt][st][2]*inv), (f16)(o[dt][st][3]*inv) };
        *(f16x4*)(ob + (size_t)(bg*49 + sq)*512 + head*64 + d0) = h4;
      }
    }
  }
}

// ---------------------------------------------------------------------------
// k_proj: C[d][row_w] = sum_c Wp[d][c] * A[row_w][c]; +bias; scatter to token
//   same T4 pipelined GEMM core + XCD-grouped 1-D grid (4 tiles/XCD group)
// ---------------------------------------------------------------------------
__global__ __launch_bounds__(256) void k_proj(
    const f16* __restrict__ a16, const f16* __restrict__ w16,
    const float* __restrict__ bias, float* __restrict__ out)
{
  __shared__ __align__(16) f16 Wt[2][128*64];
  __shared__ __align__(16) f16 Xt[2][128*64];
  const int bid = blockIdx.x;          // 0..3135
  const int xcd = bid & 7;
  const int jj  = bid >> 3;            // 0..391
  const int qq  = jj >> 2;             // 0..97
  const int by  = jj & 3;              // channel tile 0..3
  const int bx  = xcd + qq*8;          // windowed-row tile 0..783

  const f16* gW = w16 + (size_t)(by*128)*512;
  const f16* gX = a16 + (size_t)(bx*128)*512;
  GEMM_PRELUDE();

  f32x4 acc[4][4] = {};
  GEMM_LOOP();

#pragma unroll
  for (int j = 0; j < 4; ++j) {
    int m  = bx*128 + wp*64 + j*16 + l15;   // windowed row
    int b  = m / 3136;
    int rr = m - b*3136;
    int g  = rr / 49;
    int s  = rr - g*49;
    int gh = g >> 3, gw = g & 7;
    int p  = s / 7,  qx = s - p*7;
    int hh = gh*7 + p, ww = gw*7 + qx;
    size_t tok = (size_t)b*3136 + hh*56 + ww;
#pragma unroll
    for (int i = 0; i < 4; ++i) {
      int d0 = by*128 + wq*64 + i*16 + quad*4;
      float4 bb = *(const float4*)(bias + d0);
      float4 o4 = make_float4(acc[i][j][0]+bb.x, acc[i][j][1]+bb.y,
                              acc[i][j][2]+bb.z, acc[i][j][3]+bb.w);
      *(float4*)(out + tok*512 + d0) = o4;
    }
  }
}

// ---------------------------------------------------------------------------
extern "C" void kernel_launch(void* const* d_in, const int* in_sizes, int n_in,
                              void* d_out, int out_size, void* d_ws, size_t ws_size,
                              hipStream_t stream) {
  const float* x     = (const float*)d_in[0];
  const float* wqkv  = (const float*)d_in[1];
  const float* wproj = (const float*)d_in[2];
  const float* bias  = (const float*)d_in[3];

  char* ws = (char*)d_ws;
  // ws layout (bytes):
  //   [0, 102760448)            x16  -> later aliased by attn_out (fp16)
  //   [102760448, 104333312)    wqkv16
  //   [104333312, 104857600)    wproj16
  //   [104857600, +12544)       rope table (float2[49*32])
  //   [104873984, +102768640)   v [bgh][49][64] fp16 (+8KB pad for Vt staging overrun)
  f16*    x16   = (f16*)(ws);
  f16*    wq16  = (f16*)(ws + 102760448);
  f16*    wp16  = (f16*)(ws + 104333312);
  float2* tab   = (float2*)(ws + 104857600);
  f16*    vbuf  = (f16*)(ws + 104873984);
  f16*    attn16 = (f16*)(ws);              // aliases x16 (dead after k_qkv)

  // q,k live inside d_out (205,520,896 bytes); dead before k_proj writes
  f16* qbuf = (f16*)d_out;
  f16* kbuf = (f16*)((char*)d_out + 102760448);
  float* out = (float*)d_out;

  k_prep<<<dim3(25088 + 384 + 128 + 7), dim3(256), 0, stream>>>(
      x, wqkv, wproj, x16, wq16, wp16, tab);
  k_qkv<<<dim3(9408), dim3(256), 0, stream>>>(x16, wq16, tab, qbuf, kbuf, vbuf);
  k_attn<<<dim3(16384), dim3(64), 0, stream>>>(qbuf, kbuf, vbuf, attn16);
  k_proj<<<dim3(3136), dim3(256), 0, stream>>>(attn16, wp16, bias, out);
}

// Round 5
// 844.821 us; speedup vs baseline: 1.0968x; 1.0071x over previous
//
#include <hip/hip_runtime.h>
#include <stdint.h>
#include <stddef.h>

typedef _Float16 f16;
typedef _Float16 f16x8 __attribute__((ext_vector_type(8)));
typedef _Float16 f16x4 __attribute__((ext_vector_type(4)));
typedef float    f32x4 __attribute__((ext_vector_type(4)));

#define AS1 __attribute__((address_space(1)))
#define AS3 __attribute__((address_space(3)))

__device__ __forceinline__ void gl_lds16(const f16* g, f16* l) {
  // async global->LDS, 16B per lane; LDS dest is uniform base + lane*16
  __builtin_amdgcn_global_load_lds((const AS1 uint32_t*)g, (AS3 uint32_t*)l, 16, 0, 0);
}

// Problem constants: B=32, H=W=56, C=512, nh=8, hd=64, ws=7, S=49, G=64
// tokens/batch = 3136, M_total = 100352

// ---------------------------------------------------------------------------
// k_prep: fp32->fp16 conversions + RoPE table (49 x 32 float2 cos/sin)
//   (byte-identical to the measured 882us baseline)
// ---------------------------------------------------------------------------
__global__ __launch_bounds__(256) void k_prep(
    const float* __restrict__ x, const float* __restrict__ wqkv,
    const float* __restrict__ wproj,
    f16* __restrict__ x16, f16* __restrict__ wqkv16, f16* __restrict__ wproj16,
    float2* __restrict__ tab)
{
  const int XB = 25088, WQ = 384, WP = 128;  // blocks per region (8 elems/thread)
  int b = blockIdx.x, t = threadIdx.x;
  const float* src; f16* dst; long i0;
  if (b < XB)            { src = x;     dst = x16;     i0 = ((long)b*256 + t)*8; }
  else if (b < XB+WQ)    { src = wqkv;  dst = wqkv16;  i0 = ((long)(b-XB)*256 + t)*8; }
  else if (b < XB+WQ+WP) { src = wproj; dst = wproj16; i0 = ((long)(b-XB-WQ)*256 + t)*8; }
  else {
    int id = (b - XB - WQ - WP)*256 + t;
    if (id < 49*32) {
      int s = id >> 5, i = id & 31, j = i >> 1;
      float freq = expf(-(float)(4*j)*(1.0f/64.0f)*9.210340372f); // 10000^(-4j/64)
      float pos = (i & 1) ? (float)(s/7) : (float)(s%7);          // odd=y, even=x
      float a = pos * freq;
      tab[id] = make_float2(cosf(a), sinf(a));
    }
    return;
  }
  const float4* s4 = (const float4*)(src + i0);
  float4 v0 = s4[0], v1 = s4[1];
  f16x8 h = { (f16)v0.x,(f16)v0.y,(f16)v0.z,(f16)v0.w,
              (f16)v1.x,(f16)v1.y,(f16)v1.z,(f16)v1.w };
  *(f16x8*)(dst + i0) = h;
}

// ---------------------------------------------------------------------------
// GEMM core (shared by k_qkv / k_proj): BK=64, 128x128 tile, XOR-swizzled LDS,
// double-buffered with T4 COUNTED vmcnt: the loop never drains vmcnt to 0.
// (measured: round 4, k_qkv 323.7us, MfmaUtil 20.6, FETCH 59MB — unchanged)
// ---------------------------------------------------------------------------
#define GEMM_PRELUDE()                                                        \
  const int tid = threadIdx.x;                                                \
  const int wave = tid >> 6, ln = tid & 63;                                   \
  const int l15 = ln & 15, quad = ln >> 4;                                    \
  const int wq = wave >> 1, wp = wave & 1;                                    \
  const int srow = ln >> 3, schunk = (ln & 7) ^ srow;                         \
  const f16* pW[4]; const f16* pX[4];                                         \
  _Pragma("unroll")                                                           \
  for (int ii = 0; ii < 4; ++ii) {                                            \
    size_t ro = (size_t)(wave*32 + ii*8 + srow)*512 + schunk*8;               \
    pW[ii] = gW + ro; pX[ii] = gX + ro;                                       \
  }

#define GEMM_STAGE(bsel, kt)                                                  \
  _Pragma("unroll")                                                           \
  for (int ii = 0; ii < 4; ++ii) {                                            \
    gl_lds16(pW[ii] + (kt)*64, &Wt[bsel][(wave*32 + ii*8)*64]);               \
    gl_lds16(pX[ii] + (kt)*64, &Xt[bsel][(wave*32 + ii*8)*64]);               \
  }

#define GEMM_MAIN(bsel)                                                       \
  _Pragma("unroll")                                                           \
  for (int k2 = 0; k2 < 2; ++k2) {                                            \
    f16x8 af[4], bf[4];                                                       \
    int pc = ((k2 * 4 + quad) ^ (l15 & 7)) * 8;                               \
    _Pragma("unroll")                                                         \
    for (int i = 0; i < 4; ++i)                                               \
      af[i] = *(const f16x8*)&Wt[bsel][(wq * 64 + i * 16 + l15) * 64 + pc];   \
    _Pragma("unroll")                                                         \
    for (int j = 0; j < 4; ++j)                                               \
      bf[j] = *(const f16x8*)&Xt[bsel][(wp * 64 + j * 16 + l15) * 64 + pc];   \
    _Pragma("unroll")                                                         \
    for (int i = 0; i < 4; ++i)                                               \
      _Pragma("unroll")                                                       \
      for (int j = 0; j < 4; ++j)                                             \
        acc[i][j] = __builtin_amdgcn_mfma_f32_16x16x32_f16(af[i], bf[j],      \
                                                           acc[i][j], 0, 0, 0);\
  }

// T4 schedule. Per iter kt:
//   stage(kt+1)                      [8 loads issued; <=16 outstanding]
//   s_waitcnt vmcnt(8)               [stage(kt) landed; kt+1 still flying]
//   s_barrier                        [buf[kt] globally ready]
//   ds_reads + MFMA on buf[kt]
//   s_waitcnt lgkmcnt(0); s_barrier  [all waves done reading buf[kt] ->
//                                     safe for iter kt+1 to overwrite buf[kt]]
#define GEMM_LOOP()                                                           \
  GEMM_STAGE(0, 0);                                                           \
  _Pragma("unroll")                                                           \
  for (int kt = 0; kt < 8; ++kt) {                                            \
    if (kt < 7) {                                                             \
      GEMM_STAGE((kt + 1) & 1, kt + 1);                                       \
      asm volatile("s_waitcnt vmcnt(8)" ::: "memory");                        \
    } else {                                                                  \
      asm volatile("s_waitcnt vmcnt(0)" ::: "memory");                        \
    }                                                                         \
    __builtin_amdgcn_sched_barrier(0);                                        \
    __builtin_amdgcn_s_barrier();                                             \
    __builtin_amdgcn_sched_barrier(0);                                        \
    GEMM_MAIN(kt & 1);                                                        \
    if (kt < 7) {                                                             \
      asm volatile("s_waitcnt lgkmcnt(0)" ::: "memory");                      \
      __builtin_amdgcn_sched_barrier(0);                                      \
      __builtin_amdgcn_s_barrier();                                           \
    }                                                                         \
  }

// ---------------------------------------------------------------------------
// k_qkv: C[ch][tok] = sum_k W[ch][k] * X[tok][k]
//   1-D grid, XCD-grouped: all 12 channel-tiles of one token-tile land on the
//   same XCD (bid%8) so the X tile is filled into exactly one L2.
//   epilogue: RoPE on q/k; q,k,v all stored [bgh][s][64] (coalesced f16x4)
// ---------------------------------------------------------------------------
__global__ __launch_bounds__(256) void k_qkv(
    const f16* __restrict__ x16, const f16* __restrict__ w16,
    const float2* __restrict__ tab,
    f16* __restrict__ qb, f16* __restrict__ kb, f16* __restrict__ vb)
{
  __shared__ __align__(16) f16 Wt[2][128*64];
  __shared__ __align__(16) f16 Xt[2][128*64];
  // decode: xcd = bid&7 ; within an XCD, 12 consecutive channel-tiles share bx
  const int bid = blockIdx.x;          // 0..9407
  const int xcd = bid & 7;
  const int jj  = bid >> 3;            // 0..1175
  const int qq  = jj / 12;             // 0..97
  const int by  = jj - qq*12;          // channel tile 0..11 (0-3 q, 4-7 k, 8-11 v)
  const int bx  = xcd + qq*8;          // token tile 0..783

  const f16* gW = w16 + (size_t)(by*128)*512;
  const f16* gX = x16 + (size_t)(bx*128)*512;
  GEMM_PRELUDE();

  f32x4 acc[4][4] = {};
  GEMM_LOOP();

  const int t = (by*128) >> 9;   // 0=q,1=k,2=v (uniform per block)
#pragma unroll
  for (int j = 0; j < 4; ++j) {
    int m  = bx*128 + wp*64 + j*16 + l15;   // token (token-order)
    int b  = m / 3136;
    int nn = m - b*3136;
    int hh = nn / 56, ww = nn - hh*56;
    int gh = hh / 7,  p  = hh - gh*7;
    int gw = ww / 7,  qx = ww - gw*7;
    int g  = gh*8 + gw;
    int s  = p*7 + qx;
    int bg = b*64 + g;
#pragma unroll
    for (int i = 0; i < 4; ++i) {
      int c0   = by*128 + wq*64 + i*16 + quad*4;  // global channel of reg 0
      int cin  = c0 & 511;
      int head = cin >> 6;
      int dd   = cin & 63;                        // multiple of 4
      float v0 = acc[i][j][0], v1 = acc[i][j][1], v2 = acc[i][j][2], v3 = acc[i][j][3];
      f16x4 h4;
      if (t < 2) {
        float2 t0 = tab[s*32 + (dd >> 1)];
        float2 t1 = tab[s*32 + (dd >> 1) + 1];
        h4[0] = (f16)(v0*t0.x - v1*t0.y);
        h4[1] = (f16)(v0*t0.y + v1*t0.x);
        h4[2] = (f16)(v2*t1.x - v3*t1.y);
        h4[3] = (f16)(v2*t1.y + v3*t1.x);
      } else {
        h4[0] = (f16)v0; h4[1] = (f16)v1; h4[2] = (f16)v2; h4[3] = (f16)v3;
      }
      f16* dst = (t == 0 ? qb : (t == 1 ? kb : vb))
               + (size_t)((bg*8 + head)*49 + s)*64 + dd;
      *(f16x4*)dst = h4;
    }
  }
}

// ---------------------------------------------------------------------------
// k_attn: one wave per (b,g,head), 3 wave-jobs per 192-thread block.
//   All LDS is wave-private -> no __syncthreads; per-wave s_waitcnt instead.
//   LDS 3*17.4KB = 52.9KB -> 3 blocks/CU = 9 waves/CU (vs 5 with 1-wave blocks)
//   S=49 padded to 64 via clamp+mask. V staged to LDS, V^T via ds_read_u16.
// ---------------------------------------------------------------------------
__global__ __launch_bounds__(192) void k_attn(
    const f16* __restrict__ qb, const f16* __restrict__ kb,
    const f16* __restrict__ vb, f16* __restrict__ ob)
{
  __shared__ __align__(16) f16 VtA[3][64*64];  // rows 49..63 garbage, masked by P=0
  __shared__ __align__(16) f16 PA[3][64*72];   // unnormalized exp, stride 72 (144B)
  __shared__ float lsumA[3][64];
  const int wave = threadIdx.x >> 6;
  const int bid  = blockIdx.x*3 + wave;
  if (bid >= 16384) return;                    // wave-uniform; no barriers below
  f16* Vt = VtA[wave];
  f16* P  = PA[wave];
  float* lsum = lsumA[wave];
  const int ln = threadIdx.x & 63, l15 = ln & 15, quad = ln >> 4;
  const f16* q = qb + (size_t)bid*(49*64);
  const f16* k = kb + (size_t)bid*(49*64);
  const f16* v = vb + (size_t)bid*(49*64);

  // stage V: 64 rows x 128 B (reads 15 rows past this window; vb is padded)
#pragma unroll
  for (int i = 0; i < 8; ++i)
    gl_lds16(v + (size_t)(i*8 + (ln>>3))*64 + (ln&7)*8, Vt + i*512);

  // ---- logits = Q K^T
  f32x4 a[4][4] = {};
#pragma unroll
  for (int kt = 0; kt < 2; ++kt) {
    f16x8 qf[4], kf[4];
#pragma unroll
    for (int mt = 0; mt < 4; ++mt) {
      int s = mt*16 + l15; if (s > 48) s = 48;   // clamp pad rows (masked later)
      qf[mt] = *(const f16x8*)(q + s*64 + kt*32 + quad*8);
      kf[mt] = *(const f16x8*)(k + s*64 + kt*32 + quad*8);
    }
#pragma unroll
    for (int mt = 0; mt < 4; ++mt)
#pragma unroll
      for (int nt = 0; nt < 4; ++nt)
        a[mt][nt] = __builtin_amdgcn_mfma_f32_16x16x32_f16(qf[mt], kf[nt], a[mt][nt], 0, 0, 0);
  }

  // ---- softmax rows (row = s_q = mt*16 + quad*4 + r ; col = s_k = nt*16 + l15)
  const float scale = 0.125f;
#pragma unroll
  for (int mt = 0; mt < 4; ++mt) {
    float mx[4] = {-1e30f,-1e30f,-1e30f,-1e30f};
#pragma unroll
    for (int nt = 0; nt < 4; ++nt) {
      int col = nt*16 + l15;
      bool valid = col < 49;
#pragma unroll
      for (int r = 0; r < 4; ++r) {
        float vv = valid ? a[mt][nt][r]*scale : -1e30f;
        a[mt][nt][r] = vv;
        mx[r] = fmaxf(mx[r], vv);
      }
    }
#pragma unroll
    for (int d = 1; d < 16; d <<= 1)
#pragma unroll
      for (int r = 0; r < 4; ++r) mx[r] = fmaxf(mx[r], __shfl_xor(mx[r], d, 64));
    float sm[4] = {0.f,0.f,0.f,0.f};
#pragma unroll
    for (int nt = 0; nt < 4; ++nt)
#pragma unroll
      for (int r = 0; r < 4; ++r) {
        float e = __expf(a[mt][nt][r] - mx[r]);
        a[mt][nt][r] = e;
        sm[r] += e;
      }
#pragma unroll
    for (int d = 1; d < 16; d <<= 1)
#pragma unroll
      for (int r = 0; r < 4; ++r) sm[r] += __shfl_xor(sm[r], d, 64);
#pragma unroll
    for (int nt = 0; nt < 4; ++nt)
#pragma unroll
      for (int r = 0; r < 4; ++r)
        P[(mt*16 + quad*4 + r)*72 + nt*16 + l15] = (f16)a[mt][nt][r];
    if (l15 == 0) {
#pragma unroll
      for (int r = 0; r < 4; ++r) lsum[mt*16 + quad*4 + r] = sm[r];
    }
  }
  // drain: V staging (vmcnt) + P/lsum writes (lgkmcnt); wave-private, no barrier
  asm volatile("s_waitcnt vmcnt(0) lgkmcnt(0)" ::: "memory");
  __builtin_amdgcn_sched_barrier(0);

  // ---- O^T[d][s_q] = sum_s V^T[d][s] * P[s_q][s]   (A=V^T rows, B=P rows)
  f32x4 o[4][4] = {};
#pragma unroll
  for (int kt = 0; kt < 2; ++kt) {
    const int s0 = kt*32 + quad*8;
    f16x8 vf[4], pf[4];
#pragma unroll
    for (int dt = 0; dt < 4; ++dt)
#pragma unroll
      for (int j = 0; j < 8; ++j)
        vf[dt][j] = Vt[(s0 + j)*64 + dt*16 + l15];
#pragma unroll
    for (int st = 0; st < 4; ++st) pf[st] = *(const f16x8*)&P[(st*16 + l15)*72 + s0];
#pragma unroll
    for (int dt = 0; dt < 4; ++dt)
#pragma unroll
      for (int st = 0; st < 4; ++st)
        o[dt][st] = __builtin_amdgcn_mfma_f32_16x16x32_f16(vf[dt], pf[st], o[dt][st], 0, 0, 0);
  }

  const int bg = bid >> 3, head = bid & 7;
#pragma unroll
  for (int st = 0; st < 4; ++st) {
    int sq = st*16 + l15;
    if (sq < 49) {
      float inv = 1.0f / lsum[sq];
#pragma unroll
      for (int dt = 0; dt < 4; ++dt) {
        int d0 = dt*16 + quad*4;
        f16x4 h4 = { (f16)(o[dt][st][0]*inv), (f16)(o[dt][st][1]*inv),
                     (f16)(o[dt][st][2]*inv), (f16)(o[dt][st][3]*inv) };
        *(f16x4*)(ob + (size_t)(bg*49 + sq)*512 + head*64 + d0) = h4;
      }
    }
  }
}

// ---------------------------------------------------------------------------
// k_proj: C[d][row_w] = sum_c Wp[d][c] * A[row_w][c]; +bias; scatter to token
//   same T4 pipelined GEMM core + XCD-grouped 1-D grid (4 tiles/XCD group)
// ---------------------------------------------------------------------------
__global__ __launch_bounds__(256) void k_proj(
    const f16* __restrict__ a16, const f16* __restrict__ w16,
    const float* __restrict__ bias, float* __restrict__ out)
{
  __shared__ __align__(16) f16 Wt[2][128*64];
  __shared__ __align__(16) f16 Xt[2][128*64];
  const int bid = blockIdx.x;          // 0..3135
  const int xcd = bid & 7;
  const int jj  = bid >> 3;            // 0..391
  const int qq  = jj >> 2;             // 0..97
  const int by  = jj & 3;              // channel tile 0..3
  const int bx  = xcd + qq*8;          // windowed-row tile 0..783

  const f16* gW = w16 + (size_t)(by*128)*512;
  const f16* gX = a16 + (size_t)(bx*128)*512;
  GEMM_PRELUDE();

  f32x4 acc[4][4] = {};
  GEMM_LOOP();

#pragma unroll
  for (int j = 0; j < 4; ++j) {
    int m  = bx*128 + wp*64 + j*16 + l15;   // windowed row
    int b  = m / 3136;
    int rr = m - b*3136;
    int g  = rr / 49;
    int s  = rr - g*49;
    int gh = g >> 3, gw = g & 7;
    int p  = s / 7,  qx = s - p*7;
    int hh = gh*7 + p, ww = gw*7 + qx;
    size_t tok = (size_t)b*3136 + hh*56 + ww;
#pragma unroll
    for (int i = 0; i < 4; ++i) {
      int d0 = by*128 + wq*64 + i*16 + quad*4;
      float4 bb = *(const float4*)(bias + d0);
      float4 o4 = make_float4(acc[i][j][0]+bb.x, acc[i][j][1]+bb.y,
                              acc[i][j][2]+bb.z, acc[i][j][3]+bb.w);
      *(float4*)(out + tok*512 + d0) = o4;
    }
  }
}

// ---------------------------------------------------------------------------
extern "C" void kernel_launch(void* const* d_in, const int* in_sizes, int n_in,
                              void* d_out, int out_size, void* d_ws, size_t ws_size,
                              hipStream_t stream) {
  const float* x     = (const float*)d_in[0];
  const float* wqkv  = (const float*)d_in[1];
  const float* wproj = (const float*)d_in[2];
  const float* bias  = (const float*)d_in[3];

  char* ws = (char*)d_ws;
  // ws layout (bytes):
  //   [0, 102760448)            x16  -> later aliased by attn_out (fp16)
  //   [102760448, 104333312)    wqkv16
  //   [104333312, 104857600)    wproj16
  //   [104857600, +12544)       rope table (float2[49*32])
  //   [104873984, +102768640)   v [bgh][49][64] fp16 (+8KB pad for Vt staging overrun)
  f16*    x16   = (f16*)(ws);
  f16*    wq16  = (f16*)(ws + 102760448);
  f16*    wp16  = (f16*)(ws + 104333312);
  float2* tab   = (float2*)(ws + 104857600);
  f16*    vbuf  = (f16*)(ws + 104873984);
  f16*    attn16 = (f16*)(ws);              // aliases x16 (dead after k_qkv)

  // q,k live inside d_out (205,520,896 bytes); dead before k_proj writes
  f16* qbuf = (f16*)d_out;
  f16* kbuf = (f16*)((char*)d_out + 102760448);
  float* out = (float*)d_out;

  k_prep<<<dim3(25088 + 384 + 128 + 7), dim3(256), 0, stream>>>(
      x, wqkv, wproj, x16, wq16, wp16, tab);
  k_qkv<<<dim3(9408), dim3(256), 0, stream>>>(x16, wq16, tab, qbuf, kbuf, vbuf);
  k_attn<<<dim3(5462), dim3(192), 0, stream>>>(qbuf, kbuf, vbuf, attn16);
  k_proj<<<dim3(3136), dim3(256), 0, stream>>>(attn16, wp16, bias, out);
}

// Round 6
// 815.059 us; speedup vs baseline: 1.1368x; 1.0365x over previous
//
#include <hip/hip_runtime.h>
#include <stdint.h>
#include <stddef.h>

typedef _Float16 f16;
typedef _Float16 f16x8 __attribute__((ext_vector_type(8)));
typedef _Float16 f16x4 __attribute__((ext_vector_type(4)));
typedef float    f32x4 __attribute__((ext_vector_type(4)));

#define AS1 __attribute__((address_space(1)))
#define AS3 __attribute__((address_space(3)))

__device__ __forceinline__ void gl_lds16(const f16* g, f16* l) {
  // async global->LDS, 16B per lane; LDS dest is uniform base + lane*16
  __builtin_amdgcn_global_load_lds((const AS1 uint32_t*)g, (AS3 uint32_t*)l, 16, 0, 0);
}

// Problem constants: B=32, H=W=56, C=512, nh=8, hd=64, ws=7, S=49, G=64
// tokens/batch = 3136, M_total = 100352

// ---------------------------------------------------------------------------
// k_prep: fp32->fp16 conversions + RoPE table (49 x 32 float2 cos/sin)
//   (byte-identical to the measured 882us baseline)
// ---------------------------------------------------------------------------
__global__ __launch_bounds__(256) void k_prep(
    const float* __restrict__ x, const float* __restrict__ wqkv,
    const float* __restrict__ wproj,
    f16* __restrict__ x16, f16* __restrict__ wqkv16, f16* __restrict__ wproj16,
    float2* __restrict__ tab)
{
  const int XB = 25088, WQ = 384, WP = 128;  // blocks per region (8 elems/thread)
  int b = blockIdx.x, t = threadIdx.x;
  const float* src; f16* dst; long i0;
  if (b < XB)            { src = x;     dst = x16;     i0 = ((long)b*256 + t)*8; }
  else if (b < XB+WQ)    { src = wqkv;  dst = wqkv16;  i0 = ((long)(b-XB)*256 + t)*8; }
  else if (b < XB+WQ+WP) { src = wproj; dst = wproj16; i0 = ((long)(b-XB-WQ)*256 + t)*8; }
  else {
    int id = (b - XB - WQ - WP)*256 + t;
    if (id < 49*32) {
      int s = id >> 5, i = id & 31, j = i >> 1;
      float freq = expf(-(float)(4*j)*(1.0f/64.0f)*9.210340372f); // 10000^(-4j/64)
      float pos = (i & 1) ? (float)(s/7) : (float)(s%7);          // odd=y, even=x
      float a = pos * freq;
      tab[id] = make_float2(cosf(a), sinf(a));
    }
    return;
  }
  const float4* s4 = (const float4*)(src + i0);
  float4 v0 = s4[0], v1 = s4[1];
  f16x8 h = { (f16)v0.x,(f16)v0.y,(f16)v0.z,(f16)v0.w,
              (f16)v1.x,(f16)v1.y,(f16)v1.z,(f16)v1.w };
  *(f16x8*)(dst + i0) = h;
}

// ---------------------------------------------------------------------------
// GEMM core (shared by k_qkv / k_proj): BK=32, 128x128 tile, XOR-swizzled LDS,
// double-buffered with T4 COUNTED vmcnt. BK=32 halves LDS to 32KB total ->
// 5 blocks/CU (was 2 at BK=64); cross-block wave overlap (m114) covers the
// per-step barrier stalls.
// LDS rows are 32 f16 = 64 B = 4 chunks of 16B; chunk c of row r stored at
// physical c ^ ((r>>2)&3). Per-16-lane read phase each bank-slot gets exactly
// 2 lanes -> conflict-free (verified 0 SQ_LDS_BANK_CONFLICT on the BK=64
// analog of this scheme).
// ---------------------------------------------------------------------------
#define GEMM_PRELUDE()                                                        \
  const int tid = threadIdx.x;                                                \
  const int wave = tid >> 6, ln = tid & 63;                                   \
  const int l15 = ln & 15, quad = ln >> 4;                                    \
  const int wq = wave >> 1, wp = wave & 1;                                    \
  const int srow = ln >> 2;                   /* 0..15 rows per 1KB instr */  \
  const int schunk = (ln & 3) ^ ((ln >> 4) & 3); /* swizzled 16B chunk   */   \
  const f16* pW[2]; const f16* pX[2];                                         \
  _Pragma("unroll")                                                           \
  for (int ii = 0; ii < 2; ++ii) {                                            \
    size_t ro = (size_t)(wave*32 + ii*16 + srow)*512 + schunk*8;              \
    pW[ii] = gW + ro; pX[ii] = gX + ro;                                       \
  }

#define GEMM_STAGE(bsel, kt)                                                  \
  _Pragma("unroll")                                                           \
  for (int ii = 0; ii < 2; ++ii) {                                            \
    gl_lds16(pW[ii] + (kt)*32, &Wt[bsel][(wave*32 + ii*16)*32]);              \
    gl_lds16(pX[ii] + (kt)*32, &Xt[bsel][(wave*32 + ii*16)*32]);              \
  }

#define GEMM_MAIN(bsel)                                                       \
  {                                                                           \
    f16x8 af[4], bf[4];                                                       \
    int pc = (quad ^ ((l15 >> 2) & 3)) * 8;                                   \
    _Pragma("unroll")                                                         \
    for (int i = 0; i < 4; ++i)                                               \
      af[i] = *(const f16x8*)&Wt[bsel][(wq * 64 + i * 16 + l15) * 32 + pc];   \
    _Pragma("unroll")                                                         \
    for (int j = 0; j < 4; ++j)                                               \
      bf[j] = *(const f16x8*)&Xt[bsel][(wp * 64 + j * 16 + l15) * 32 + pc];   \
    _Pragma("unroll")                                                         \
    for (int i = 0; i < 4; ++i)                                               \
      _Pragma("unroll")                                                       \
      for (int j = 0; j < 4; ++j)                                             \
        acc[i][j] = __builtin_amdgcn_mfma_f32_16x16x32_f16(af[i], bf[j],      \
                                                           acc[i][j], 0, 0, 0);\
  }

// T4 schedule, 16 K-steps. Per iter kt:
//   stage(kt+1)                      [4 loads issued; <=8 outstanding]
//   s_waitcnt vmcnt(4)               [stage(kt) landed; kt+1 still flying]
//   s_barrier                        [buf[kt] globally ready]
//   ds_reads + MFMA on buf[kt]
//   s_waitcnt lgkmcnt(0); s_barrier  [all waves done reading buf[kt] ->
//                                     safe for iter kt+1 to overwrite buf[kt]]
#define GEMM_LOOP()                                                           \
  GEMM_STAGE(0, 0);                                                           \
  _Pragma("unroll")                                                           \
  for (int kt = 0; kt < 16; ++kt) {                                           \
    if (kt < 15) {                                                            \
      GEMM_STAGE((kt + 1) & 1, kt + 1);                                       \
      asm volatile("s_waitcnt vmcnt(4)" ::: "memory");                        \
    } else {                                                                  \
      asm volatile("s_waitcnt vmcnt(0)" ::: "memory");                        \
    }                                                                         \
    __builtin_amdgcn_sched_barrier(0);                                        \
    __builtin_amdgcn_s_barrier();                                             \
    __builtin_amdgcn_sched_barrier(0);                                        \
    GEMM_MAIN(kt & 1);                                                        \
    if (kt < 15) {                                                            \
      asm volatile("s_waitcnt lgkmcnt(0)" ::: "memory");                      \
      __builtin_amdgcn_sched_barrier(0);                                      \
      __builtin_amdgcn_s_barrier();                                           \
    }                                                                         \
  }

// ---------------------------------------------------------------------------
// k_qkv: C[ch][tok] = sum_k W[ch][k] * X[tok][k]
//   1-D grid, XCD-grouped: all 12 channel-tiles of one token-tile land on the
//   same XCD (bid%8) so the X tile is filled into exactly one L2.
//   epilogue: RoPE on q/k; q,k,v all stored [bgh][s][64] (coalesced f16x4)
// ---------------------------------------------------------------------------
__global__ __launch_bounds__(256) void k_qkv(
    const f16* __restrict__ x16, const f16* __restrict__ w16,
    const float2* __restrict__ tab,
    f16* __restrict__ qb, f16* __restrict__ kb, f16* __restrict__ vb)
{
  __shared__ __align__(16) f16 Wt[2][128*32];
  __shared__ __align__(16) f16 Xt[2][128*32];
  // decode: xcd = bid&7 ; within an XCD, 12 consecutive channel-tiles share bx
  const int bid = blockIdx.x;          // 0..9407
  const int xcd = bid & 7;
  const int jj  = bid >> 3;            // 0..1175
  const int qq  = jj / 12;             // 0..97
  const int by  = jj - qq*12;          // channel tile 0..11 (0-3 q, 4-7 k, 8-11 v)
  const int bx  = xcd + qq*8;          // token tile 0..783

  const f16* gW = w16 + (size_t)(by*128)*512;
  const f16* gX = x16 + (size_t)(bx*128)*512;
  GEMM_PRELUDE();

  f32x4 acc[4][4] = {};
  GEMM_LOOP();

  const int t = (by*128) >> 9;   // 0=q,1=k,2=v (uniform per block)
#pragma unroll
  for (int j = 0; j < 4; ++j) {
    int m  = bx*128 + wp*64 + j*16 + l15;   // token (token-order)
    int b  = m / 3136;
    int nn = m - b*3136;
    int hh = nn / 56, ww = nn - hh*56;
    int gh = hh / 7,  p  = hh - gh*7;
    int gw = ww / 7,  qx = ww - gw*7;
    int g  = gh*8 + gw;
    int s  = p*7 + qx;
    int bg = b*64 + g;
#pragma unroll
    for (int i = 0; i < 4; ++i) {
      int c0   = by*128 + wq*64 + i*16 + quad*4;  // global channel of reg 0
      int cin  = c0 & 511;
      int head = cin >> 6;
      int dd   = cin & 63;                        // multiple of 4
      float v0 = acc[i][j][0], v1 = acc[i][j][1], v2 = acc[i][j][2], v3 = acc[i][j][3];
      f16x4 h4;
      if (t < 2) {
        float2 t0 = tab[s*32 + (dd >> 1)];
        float2 t1 = tab[s*32 + (dd >> 1) + 1];
        h4[0] = (f16)(v0*t0.x - v1*t0.y);
        h4[1] = (f16)(v0*t0.y + v1*t0.x);
        h4[2] = (f16)(v2*t1.x - v3*t1.y);
        h4[3] = (f16)(v2*t1.y + v3*t1.x);
      } else {
        h4[0] = (f16)v0; h4[1] = (f16)v1; h4[2] = (f16)v2; h4[3] = (f16)v3;
      }
      f16* dst = (t == 0 ? qb : (t == 1 ? kb : vb))
               + (size_t)((bg*8 + head)*49 + s)*64 + dd;
      *(f16x4*)dst = h4;
    }
  }
}

// ---------------------------------------------------------------------------
// k_attn: one wave per (b,g,head), 3 wave-jobs per 192-thread block.
//   All LDS is wave-private -> no __syncthreads; per-wave s_waitcnt instead.
//   (byte-identical to the measured round-5 version)
// ---------------------------------------------------------------------------
__global__ __launch_bounds__(192) void k_attn(
    const f16* __restrict__ qb, const f16* __restrict__ kb,
    const f16* __restrict__ vb, f16* __restrict__ ob)
{
  __shared__ __align__(16) f16 VtA[3][64*64];  // rows 49..63 garbage, masked by P=0
  __shared__ __align__(16) f16 PA[3][64*72];   // unnormalized exp, stride 72 (144B)
  __shared__ float lsumA[3][64];
  const int wave = threadIdx.x >> 6;
  const int bid  = blockIdx.x*3 + wave;
  if (bid >= 16384) return;                    // wave-uniform; no barriers below
  f16* Vt = VtA[wave];
  f16* P  = PA[wave];
  float* lsum = lsumA[wave];
  const int ln = threadIdx.x & 63, l15 = ln & 15, quad = ln >> 4;
  const f16* q = qb + (size_t)bid*(49*64);
  const f16* k = kb + (size_t)bid*(49*64);
  const f16* v = vb + (size_t)bid*(49*64);

  // stage V: 64 rows x 128 B (reads 15 rows past this window; vb is padded)
#pragma unroll
  for (int i = 0; i < 8; ++i)
    gl_lds16(v + (size_t)(i*8 + (ln>>3))*64 + (ln&7)*8, Vt + i*512);

  // ---- logits = Q K^T
  f32x4 a[4][4] = {};
#pragma unroll
  for (int kt = 0; kt < 2; ++kt) {
    f16x8 qf[4], kf[4];
#pragma unroll
    for (int mt = 0; mt < 4; ++mt) {
      int s = mt*16 + l15; if (s > 48) s = 48;   // clamp pad rows (masked later)
      qf[mt] = *(const f16x8*)(q + s*64 + kt*32 + quad*8);
      kf[mt] = *(const f16x8*)(k + s*64 + kt*32 + quad*8);
    }
#pragma unroll
    for (int mt = 0; mt < 4; ++mt)
#pragma unroll
      for (int nt = 0; nt < 4; ++nt)
        a[mt][nt] = __builtin_amdgcn_mfma_f32_16x16x32_f16(qf[mt], kf[nt], a[mt][nt], 0, 0, 0);
  }

  // ---- softmax rows (row = s_q = mt*16 + quad*4 + r ; col = s_k = nt*16 + l15)
  const float scale = 0.125f;
#pragma unroll
  for (int mt = 0; mt < 4; ++mt) {
    float mx[4] = {-1e30f,-1e30f,-1e30f,-1e30f};
#pragma unroll
    for (int nt = 0; nt < 4; ++nt) {
      int col = nt*16 + l15;
      bool valid = col < 49;
#pragma unroll
      for (int r = 0; r < 4; ++r) {
        float vv = valid ? a[mt][nt][r]*scale : -1e30f;
        a[mt][nt][r] = vv;
        mx[r] = fmaxf(mx[r], vv);
      }
    }
#pragma unroll
    for (int d = 1; d < 16; d <<= 1)
#pragma unroll
      for (int r = 0; r < 4; ++r) mx[r] = fmaxf(mx[r], __shfl_xor(mx[r], d, 64));
    float sm[4] = {0.f,0.f,0.f,0.f};
#pragma unroll
    for (int nt = 0; nt < 4; ++nt)
#pragma unroll
      for (int r = 0; r < 4; ++r) {
        float e = __expf(a[mt][nt][r] - mx[r]);
        a[mt][nt][r] = e;
        sm[r] += e;
      }
#pragma unroll
    for (int d = 1; d < 16; d <<= 1)
#pragma unroll
      for (int r = 0; r < 4; ++r) sm[r] += __shfl_xor(sm[r], d, 64);
#pragma unroll
    for (int nt = 0; nt < 4; ++nt)
#pragma unroll
      for (int r = 0; r < 4; ++r)
        P[(mt*16 + quad*4 + r)*72 + nt*16 + l15] = (f16)a[mt][nt][r];
    if (l15 == 0) {
#pragma unroll
      for (int r = 0; r < 4; ++r) lsum[mt*16 + quad*4 + r] = sm[r];
    }
  }
  // drain: V staging (vmcnt) + P/lsum writes (lgkmcnt); wave-private, no barrier
  asm volatile("s_waitcnt vmcnt(0) lgkmcnt(0)" ::: "memory");
  __builtin_amdgcn_sched_barrier(0);

  // ---- O^T[d][s_q] = sum_s V^T[d][s] * P[s_q][s]   (A=V^T rows, B=P rows)
  f32x4 o[4][4] = {};
#pragma unroll
  for (int kt = 0; kt < 2; ++kt) {
    const int s0 = kt*32 + quad*8;
    f16x8 vf[4], pf[4];
#pragma unroll
    for (int dt = 0; dt < 4; ++dt)
#pragma unroll
      for (int j = 0; j < 8; ++j)
        vf[dt][j] = Vt[(s0 + j)*64 + dt*16 + l15];
#pragma unroll
    for (int st = 0; st < 4; ++st) pf[st] = *(const f16x8*)&P[(st*16 + l15)*72 + s0];
#pragma unroll
    for (int dt = 0; dt < 4; ++dt)
#pragma unroll
      for (int st = 0; st < 4; ++st)
        o[dt][st] = __builtin_amdgcn_mfma_f32_16x16x32_f16(vf[dt], pf[st], o[dt][st], 0, 0, 0);
  }

  const int bg = bid >> 3, head = bid & 7;
#pragma unroll
  for (int st = 0; st < 4; ++st) {
    int sq = st*16 + l15;
    if (sq < 49) {
      float inv = 1.0f / lsum[sq];
#pragma unroll
      for (int dt = 0; dt < 4; ++dt) {
        int d0 = dt*16 + quad*4;
        f16x4 h4 = { (f16)(o[dt][st][0]*inv), (f16)(o[dt][st][1]*inv),
                     (f16)(o[dt][st][2]*inv), (f16)(o[dt][st][3]*inv) };
        *(f16x4*)(ob + (size_t)(bg*49 + sq)*512 + head*64 + d0) = h4;
      }
    }
  }
}

// ---------------------------------------------------------------------------
// k_proj: C[d][row_w] = sum_c Wp[d][c] * A[row_w][c]; +bias; scatter to token
//   same BK=32 T4 pipelined GEMM core + XCD-grouped 1-D grid
// ---------------------------------------------------------------------------
__global__ __launch_bounds__(256) void k_proj(
    const f16* __restrict__ a16, const f16* __restrict__ w16,
    const float* __restrict__ bias, float* __restrict__ out)
{
  __shared__ __align__(16) f16 Wt[2][128*32];
  __shared__ __align__(16) f16 Xt[2][128*32];
  const int bid = blockIdx.x;          // 0..3135
  const int xcd = bid & 7;
  const int jj  = bid >> 3;            // 0..391
  const int qq  = jj >> 2;             // 0..97
  const int by  = jj & 3;              // channel tile 0..3
  const int bx  = xcd + qq*8;          // windowed-row tile 0..783

  const f16* gW = w16 + (size_t)(by*128)*512;
  const f16* gX = a16 + (size_t)(bx*128)*512;
  GEMM_PRELUDE();

  f32x4 acc[4][4] = {};
  GEMM_LOOP();

#pragma unroll
  for (int j = 0; j < 4; ++j) {
    int m  = bx*128 + wp*64 + j*16 + l15;   // windowed row
    int b  = m / 3136;
    int rr = m - b*3136;
    int g  = rr / 49;
    int s  = rr - g*49;
    int gh = g >> 3, gw = g & 7;
    int p  = s / 7,  qx = s - p*7;
    int hh = gh*7 + p, ww = gw*7 + qx;
    size_t tok = (size_t)b*3136 + hh*56 + ww;
#pragma unroll
    for (int i = 0; i < 4; ++i) {
      int d0 = by*128 + wq*64 + i*16 + quad*4;
      float4 bb = *(const float4*)(bias + d0);
      float4 o4 = make_float4(acc[i][j][0]+bb.x, acc[i][j][1]+bb.y,
                              acc[i][j][2]+bb.z, acc[i][j][3]+bb.w);
      *(float4*)(out + tok*512 + d0) = o4;
    }
  }
}

// ---------------------------------------------------------------------------
extern "C" void kernel_launch(void* const* d_in, const int* in_sizes, int n_in,
                              void* d_out, int out_size, void* d_ws, size_t ws_size,
                              hipStream_t stream) {
  const float* x     = (const float*)d_in[0];
  const float* wqkv  = (const float*)d_in[1];
  const float* wproj = (const float*)d_in[2];
  const float* bias  = (const float*)d_in[3];

  char* ws = (char*)d_ws;
  // ws layout (bytes):
  //   [0, 102760448)            x16  -> later aliased by attn_out (fp16)
  //   [102760448, 104333312)    wqkv16
  //   [104333312, 104857600)    wproj16
  //   [104857600, +12544)       rope table (float2[49*32])
  //   [104873984, +102768640)   v [bgh][49][64] fp16 (+8KB pad for Vt staging overrun)
  f16*    x16   = (f16*)(ws);
  f16*    wq16  = (f16*)(ws + 102760448);
  f16*    wp16  = (f16*)(ws + 104333312);
  float2* tab   = (float2*)(ws + 104857600);
  f16*    vbuf  = (f16*)(ws + 104873984);
  f16*    attn16 = (f16*)(ws);              // aliases x16 (dead after k_qkv)

  // q,k live inside d_out (205,520,896 bytes); dead before k_proj writes
  f16* qbuf = (f16*)d_out;
  f16* kbuf = (f16*)((char*)d_out + 102760448);
  float* out = (float*)d_out;

  k_prep<<<dim3(25088 + 384 + 128 + 7), dim3(256), 0, stream>>>(
      x, wqkv, wproj, x16, wq16, wp16, tab);
  k_qkv<<<dim3(9408), dim3(256), 0, stream>>>(x16, wq16, tab, qbuf, kbuf, vbuf);
  k_attn<<<dim3(5462), dim3(192), 0, stream>>>(qbuf, kbuf, vbuf, attn16);
  k_proj<<<dim3(3136), dim3(256), 0, stream>>>(attn16, wp16, bias, out);
}

// Round 7
// 788.538 us; speedup vs baseline: 1.1751x; 1.0336x over previous
//
#include <hip/hip_runtime.h>
#include <stdint.h>
#include <stddef.h>

typedef _Float16 f16;
typedef _Float16 f16x8 __attribute__((ext_vector_type(8)));
typedef _Float16 f16x4 __attribute__((ext_vector_type(4)));
typedef float    f32x4 __attribute__((ext_vector_type(4)));

#define AS1 __attribute__((address_space(1)))
#define AS3 __attribute__((address_space(3)))

__device__ __forceinline__ void gl_lds16(const f16* g, f16* l) {
  // async global->LDS, 16B per lane; LDS dest is uniform base + lane*16
  __builtin_amdgcn_global_load_lds((const AS1 uint32_t*)g, (AS3 uint32_t*)l, 16, 0, 0);
}

// Problem constants: B=32, H=W=56, C=512, nh=8, hd=64, ws=7, S=49, G=64
// tokens/batch = 3136, M_total = 100352

// ---------------------------------------------------------------------------
// k_prep: fp32->fp16 conversions + RoPE table (49 x 32 float2 cos/sin)
//   (byte-identical to the measured 882us baseline)
// ---------------------------------------------------------------------------
__global__ __launch_bounds__(256) void k_prep(
    const float* __restrict__ x, const float* __restrict__ wqkv,
    const float* __restrict__ wproj,
    f16* __restrict__ x16, f16* __restrict__ wqkv16, f16* __restrict__ wproj16,
    float2* __restrict__ tab)
{
  const int XB = 25088, WQ = 384, WP = 128;  // blocks per region (8 elems/thread)
  int b = blockIdx.x, t = threadIdx.x;
  const float* src; f16* dst; long i0;
  if (b < XB)            { src = x;     dst = x16;     i0 = ((long)b*256 + t)*8; }
  else if (b < XB+WQ)    { src = wqkv;  dst = wqkv16;  i0 = ((long)(b-XB)*256 + t)*8; }
  else if (b < XB+WQ+WP) { src = wproj; dst = wproj16; i0 = ((long)(b-XB-WQ)*256 + t)*8; }
  else {
    int id = (b - XB - WQ - WP)*256 + t;
    if (id < 49*32) {
      int s = id >> 5, i = id & 31, j = i >> 1;
      float freq = expf(-(float)(4*j)*(1.0f/64.0f)*9.210340372f); // 10000^(-4j/64)
      float pos = (i & 1) ? (float)(s/7) : (float)(s%7);          // odd=y, even=x
      float a = pos * freq;
      tab[id] = make_float2(cosf(a), sinf(a));
    }
    return;
  }
  const float4* s4 = (const float4*)(src + i0);
  float4 v0 = s4[0], v1 = s4[1];
  f16x8 h = { (f16)v0.x,(f16)v0.y,(f16)v0.z,(f16)v0.w,
              (f16)v1.x,(f16)v1.y,(f16)v1.z,(f16)v1.w };
  *(f16x8*)(dst + i0) = h;
}

// ---------------------------------------------------------------------------
// GEMM core (shared by k_qkv / k_proj): BK=32, 128x128 tile, XOR-swizzled LDS,
// double-buffered with T4 COUNTED vmcnt.
// LDS rows are 32 f16 = 64 B = 4 chunks of 16B. b128 reads service 8 lanes
// per cycle (8 x 16B = 32 banks), so 8 consecutive lanes must cover all 32
// banks. Row parity alternates bank-start 0/16; the chunk xor must advance
// every 2 rows: chunk c of row r stored at physical c ^ ((r>>1)&3).
// (round-6's (r>>2) xor gave every-other-lane 2-way conflicts: 1.93e7 cyc)
// ---------------------------------------------------------------------------
#define GEMM_PRELUDE()                                                        \
  const int tid = threadIdx.x;                                                \
  const int wave = tid >> 6, ln = tid & 63;                                   \
  const int l15 = ln & 15, quad = ln >> 4;                                    \
  const int wq = wave >> 1, wp = wave & 1;                                    \
  const int srow = ln >> 2;                   /* 0..15 rows per 1KB instr */  \
  const int schunk = (ln & 3) ^ ((ln >> 3) & 3); /* xor advances per 2 rows */\
  const f16* pW[2]; const f16* pX[2];                                         \
  _Pragma("unroll")                                                           \
  for (int ii = 0; ii < 2; ++ii) {                                            \
    size_t ro = (size_t)(wave*32 + ii*16 + srow)*512 + schunk*8;              \
    pW[ii] = gW + ro; pX[ii] = gX + ro;                                       \
  }

#define GEMM_STAGE(bsel, kt)                                                  \
  _Pragma("unroll")                                                           \
  for (int ii = 0; ii < 2; ++ii) {                                            \
    gl_lds16(pW[ii] + (kt)*32, &Wt[bsel][(wave*32 + ii*16)*32]);              \
    gl_lds16(pX[ii] + (kt)*32, &Xt[bsel][(wave*32 + ii*16)*32]);              \
  }

#define GEMM_MAIN(bsel)                                                       \
  {                                                                           \
    f16x8 af[4], bf[4];                                                       \
    int pc = (quad ^ ((l15 >> 1) & 3)) * 8;                                   \
    _Pragma("unroll")                                                         \
    for (int i = 0; i < 4; ++i)                                               \
      af[i] = *(const f16x8*)&Wt[bsel][(wq * 64 + i * 16 + l15) * 32 + pc];   \
    _Pragma("unroll")                                                         \
    for (int j = 0; j < 4; ++j)                                               \
      bf[j] = *(const f16x8*)&Xt[bsel][(wp * 64 + j * 16 + l15) * 32 + pc];   \
    _Pragma("unroll")                                                         \
    for (int i = 0; i < 4; ++i)                                               \
      _Pragma("unroll")                                                       \
      for (int j = 0; j < 4; ++j)                                             \
        acc[i][j] = __builtin_amdgcn_mfma_f32_16x16x32_f16(af[i], bf[j],      \
                                                           acc[i][j], 0, 0, 0);\
  }

// T4 schedule, 16 K-steps. Per iter kt:
//   stage(kt+1)                      [4 loads issued; <=8 outstanding]
//   s_waitcnt vmcnt(4)               [stage(kt) landed; kt+1 still flying]
//   s_barrier                        [buf[kt] globally ready]
//   ds_reads + MFMA on buf[kt]
//   s_waitcnt lgkmcnt(0); s_barrier  [all waves done reading buf[kt] ->
//                                     safe for iter kt+1 to overwrite buf[kt]]
#define GEMM_LOOP()                                                           \
  GEMM_STAGE(0, 0);                                                           \
  _Pragma("unroll")                                                           \
  for (int kt = 0; kt < 16; ++kt) {                                           \
    if (kt < 15) {                                                            \
      GEMM_STAGE((kt + 1) & 1, kt + 1);                                       \
      asm volatile("s_waitcnt vmcnt(4)" ::: "memory");                        \
    } else {                                                                  \
      asm volatile("s_waitcnt vmcnt(0)" ::: "memory");                        \
    }                                                                         \
    __builtin_amdgcn_sched_barrier(0);                                        \
    __builtin_amdgcn_s_barrier();                                             \
    __builtin_amdgcn_sched_barrier(0);                                        \
    GEMM_MAIN(kt & 1);                                                        \
    if (kt < 15) {                                                            \
      asm volatile("s_waitcnt lgkmcnt(0)" ::: "memory");                      \
      __builtin_amdgcn_sched_barrier(0);                                      \
      __builtin_amdgcn_s_barrier();                                           \
    }                                                                         \
  }

// ---------------------------------------------------------------------------
// k_qkv: C[ch][tok] = sum_k W[ch][k] * X[tok][k]
//   1-D grid, XCD-grouped: all 12 channel-tiles of one token-tile land on the
//   same XCD (bid%8) so the X tile is filled into exactly one L2.
//   __launch_bounds__(256,4): cap unified regs at 128/lane -> 16 waves/CU
//   epilogue: RoPE on q/k; q,k,v all stored [bgh][s][64] (coalesced f16x4)
// ---------------------------------------------------------------------------
__global__ __launch_bounds__(256, 4) void k_qkv(
    const f16* __restrict__ x16, const f16* __restrict__ w16,
    const float2* __restrict__ tab,
    f16* __restrict__ qb, f16* __restrict__ kb, f16* __restrict__ vb)
{
  __shared__ __align__(16) f16 Wt[2][128*32];
  __shared__ __align__(16) f16 Xt[2][128*32];
  // decode: xcd = bid&7 ; within an XCD, 12 consecutive channel-tiles share bx
  const int bid = blockIdx.x;          // 0..9407
  const int xcd = bid & 7;
  const int jj  = bid >> 3;            // 0..1175
  const int qq  = jj / 12;             // 0..97
  const int by  = jj - qq*12;          // channel tile 0..11 (0-3 q, 4-7 k, 8-11 v)
  const int bx  = xcd + qq*8;          // token tile 0..783

  const f16* gW = w16 + (size_t)(by*128)*512;
  const f16* gX = x16 + (size_t)(bx*128)*512;
  GEMM_PRELUDE();

  f32x4 acc[4][4] = {};
  GEMM_LOOP();

  const int t = (by*128) >> 9;   // 0=q,1=k,2=v (uniform per block)
#pragma unroll
  for (int j = 0; j < 4; ++j) {
    int m  = bx*128 + wp*64 + j*16 + l15;   // token (token-order)
    int b  = m / 3136;
    int nn = m - b*3136;
    int hh = nn / 56, ww = nn - hh*56;
    int gh = hh / 7,  p  = hh - gh*7;
    int gw = ww / 7,  qx = ww - gw*7;
    int g  = gh*8 + gw;
    int s  = p*7 + qx;
    int bg = b*64 + g;
#pragma unroll
    for (int i = 0; i < 4; ++i) {
      int c0   = by*128 + wq*64 + i*16 + quad*4;  // global channel of reg 0
      int cin  = c0 & 511;
      int head = cin >> 6;
      int dd   = cin & 63;                        // multiple of 4
      float v0 = acc[i][j][0], v1 = acc[i][j][1], v2 = acc[i][j][2], v3 = acc[i][j][3];
      f16x4 h4;
      if (t < 2) {
        float2 t0 = tab[s*32 + (dd >> 1)];
        float2 t1 = tab[s*32 + (dd >> 1) + 1];
        h4[0] = (f16)(v0*t0.x - v1*t0.y);
        h4[1] = (f16)(v0*t0.y + v1*t0.x);
        h4[2] = (f16)(v2*t1.x - v3*t1.y);
        h4[3] = (f16)(v2*t1.y + v3*t1.x);
      } else {
        h4[0] = (f16)v0; h4[1] = (f16)v1; h4[2] = (f16)v2; h4[3] = (f16)v3;
      }
      f16* dst = (t == 0 ? qb : (t == 1 ? kb : vb))
               + (size_t)((bg*8 + head)*49 + s)*64 + dd;
      *(f16x4*)dst = h4;
    }
  }
}

// ---------------------------------------------------------------------------
// k_attn: one wave per (b,g,head), 3 wave-jobs per 192-thread block.
//   All LDS is wave-private -> no __syncthreads; per-wave s_waitcnt instead.
//   (byte-identical to the measured round-5/6 version)
// ---------------------------------------------------------------------------
__global__ __launch_bounds__(192) void k_attn(
    const f16* __restrict__ qb, const f16* __restrict__ kb,
    const f16* __restrict__ vb, f16* __restrict__ ob)
{
  __shared__ __align__(16) f16 VtA[3][64*64];  // rows 49..63 garbage, masked by P=0
  __shared__ __align__(16) f16 PA[3][64*72];   // unnormalized exp, stride 72 (144B)
  __shared__ float lsumA[3][64];
  const int wave = threadIdx.x >> 6;
  const int bid  = blockIdx.x*3 + wave;
  if (bid >= 16384) return;                    // wave-uniform; no barriers below
  f16* Vt = VtA[wave];
  f16* P  = PA[wave];
  float* lsum = lsumA[wave];
  const int ln = threadIdx.x & 63, l15 = ln & 15, quad = ln >> 4;
  const f16* q = qb + (size_t)bid*(49*64);
  const f16* k = kb + (size_t)bid*(49*64);
  const f16* v = vb + (size_t)bid*(49*64);

  // stage V: 64 rows x 128 B (reads 15 rows past this window; vb is padded)
#pragma unroll
  for (int i = 0; i < 8; ++i)
    gl_lds16(v + (size_t)(i*8 + (ln>>3))*64 + (ln&7)*8, Vt + i*512);

  // ---- logits = Q K^T
  f32x4 a[4][4] = {};
#pragma unroll
  for (int kt = 0; kt < 2; ++kt) {
    f16x8 qf[4], kf[4];
#pragma unroll
    for (int mt = 0; mt < 4; ++mt) {
      int s = mt*16 + l15; if (s > 48) s = 48;   // clamp pad rows (masked later)
      qf[mt] = *(const f16x8*)(q + s*64 + kt*32 + quad*8);
      kf[mt] = *(const f16x8*)(k + s*64 + kt*32 + quad*8);
    }
#pragma unroll
    for (int mt = 0; mt < 4; ++mt)
#pragma unroll
      for (int nt = 0; nt < 4; ++nt)
        a[mt][nt] = __builtin_amdgcn_mfma_f32_16x16x32_f16(qf[mt], kf[nt], a[mt][nt], 0, 0, 0);
  }

  // ---- softmax rows (row = s_q = mt*16 + quad*4 + r ; col = s_k = nt*16 + l15)
  const float scale = 0.125f;
#pragma unroll
  for (int mt = 0; mt < 4; ++mt) {
    float mx[4] = {-1e30f,-1e30f,-1e30f,-1e30f};
#pragma unroll
    for (int nt = 0; nt < 4; ++nt) {
      int col = nt*16 + l15;
      bool valid = col < 49;
#pragma unroll
      for (int r = 0; r < 4; ++r) {
        float vv = valid ? a[mt][nt][r]*scale : -1e30f;
        a[mt][nt][r] = vv;
        mx[r] = fmaxf(mx[r], vv);
      }
    }
#pragma unroll
    for (int d = 1; d < 16; d <<= 1)
#pragma unroll
      for (int r = 0; r < 4; ++r) mx[r] = fmaxf(mx[r], __shfl_xor(mx[r], d, 64));
    float sm[4] = {0.f,0.f,0.f,0.f};
#pragma unroll
    for (int nt = 0; nt < 4; ++nt)
#pragma unroll
      for (int r = 0; r < 4; ++r) {
        float e = __expf(a[mt][nt][r] - mx[r]);
        a[mt][nt][r] = e;
        sm[r] += e;
      }
#pragma unroll
    for (int d = 1; d < 16; d <<= 1)
#pragma unroll
      for (int r = 0; r < 4; ++r) sm[r] += __shfl_xor(sm[r], d, 64);
#pragma unroll
    for (int nt = 0; nt < 4; ++nt)
#pragma unroll
      for (int r = 0; r < 4; ++r)
        P[(mt*16 + quad*4 + r)*72 + nt*16 + l15] = (f16)a[mt][nt][r];
    if (l15 == 0) {
#pragma unroll
      for (int r = 0; r < 4; ++r) lsum[mt*16 + quad*4 + r] = sm[r];
    }
  }
  // drain: V staging (vmcnt) + P/lsum writes (lgkmcnt); wave-private, no barrier
  asm volatile("s_waitcnt vmcnt(0) lgkmcnt(0)" ::: "memory");
  __builtin_amdgcn_sched_barrier(0);

  // ---- O^T[d][s_q] = sum_s V^T[d][s] * P[s_q][s]   (A=V^T rows, B=P rows)
  f32x4 o[4][4] = {};
#pragma unroll
  for (int kt = 0; kt < 2; ++kt) {
    const int s0 = kt*32 + quad*8;
    f16x8 vf[4], pf[4];
#pragma unroll
    for (int dt = 0; dt < 4; ++dt)
#pragma unroll
      for (int j = 0; j < 8; ++j)
        vf[dt][j] = Vt[(s0 + j)*64 + dt*16 + l15];
#pragma unroll
    for (int st = 0; st < 4; ++st) pf[st] = *(const f16x8*)&P[(st*16 + l15)*72 + s0];
#pragma unroll
    for (int dt = 0; dt < 4; ++dt)
#pragma unroll
      for (int st = 0; st < 4; ++st)
        o[dt][st] = __builtin_amdgcn_mfma_f32_16x16x32_f16(vf[dt], pf[st], o[dt][st], 0, 0, 0);
  }

  const int bg = bid >> 3, head = bid & 7;
#pragma unroll
  for (int st = 0; st < 4; ++st) {
    int sq = st*16 + l15;
    if (sq < 49) {
      float inv = 1.0f / lsum[sq];
#pragma unroll
      for (int dt = 0; dt < 4; ++dt) {
        int d0 = dt*16 + quad*4;
        f16x4 h4 = { (f16)(o[dt][st][0]*inv), (f16)(o[dt][st][1]*inv),
                     (f16)(o[dt][st][2]*inv), (f16)(o[dt][st][3]*inv) };
        *(f16x4*)(ob + (size_t)(bg*49 + sq)*512 + head*64 + d0) = h4;
      }
    }
  }
}

// ---------------------------------------------------------------------------
// k_proj: C[d][row_w] = sum_c Wp[d][c] * A[row_w][c]; +bias; scatter to token
//   same BK=32 T4 pipelined GEMM core + XCD-grouped 1-D grid
// ---------------------------------------------------------------------------
__global__ __launch_bounds__(256, 4) void k_proj(
    const f16* __restrict__ a16, const f16* __restrict__ w16,
    const float* __restrict__ bias, float* __restrict__ out)
{
  __shared__ __align__(16) f16 Wt[2][128*32];
  __shared__ __align__(16) f16 Xt[2][128*32];
  const int bid = blockIdx.x;          // 0..3135
  const int xcd = bid & 7;
  const int jj  = bid >> 3;            // 0..391
  const int qq  = jj >> 2;             // 0..97
  const int by  = jj & 3;              // channel tile 0..3
  const int bx  = xcd + qq*8;          // windowed-row tile 0..783

  const f16* gW = w16 + (size_t)(by*128)*512;
  const f16* gX = a16 + (size_t)(bx*128)*512;
  GEMM_PRELUDE();

  f32x4 acc[4][4] = {};
  GEMM_LOOP();

#pragma unroll
  for (int j = 0; j < 4; ++j) {
    int m  = bx*128 + wp*64 + j*16 + l15;   // windowed row
    int b  = m / 3136;
    int rr = m - b*3136;
    int g  = rr / 49;
    int s  = rr - g*49;
    int gh = g >> 3, gw = g & 7;
    int p  = s / 7,  qx = s - p*7;
    int hh = gh*7 + p, ww = gw*7 + qx;
    size_t tok = (size_t)b*3136 + hh*56 + ww;
#pragma unroll
    for (int i = 0; i < 4; ++i) {
      int d0 = by*128 + wq*64 + i*16 + quad*4;
      float4 bb = *(const float4*)(bias + d0);
      float4 o4 = make_float4(acc[i][j][0]+bb.x, acc[i][j][1]+bb.y,
                              acc[i][j][2]+bb.z, acc[i][j][3]+bb.w);
      *(float4*)(out + tok*512 + d0) = o4;
    }
  }
}

// ---------------------------------------------------------------------------
extern "C" void kernel_launch(void* const* d_in, const int* in_sizes, int n_in,
                              void* d_out, int out_size, void* d_ws, size_t ws_size,
                              hipStream_t stream) {
  const float* x     = (const float*)d_in[0];
  const float* wqkv  = (const float*)d_in[1];
  const float* wproj = (const float*)d_in[2];
  const float* bias  = (const float*)d_in[3];

  char* ws = (char*)d_ws;
  // ws layout (bytes):
  //   [0, 102760448)            x16  -> later aliased by attn_out (fp16)
  //   [102760448, 104333312)    wqkv16
  //   [104333312, 104857600)    wproj16
  //   [104857600, +12544)       rope table (float2[49*32])
  //   [104873984, +102768640)   v [bgh][49][64] fp16 (+8KB pad for Vt staging overrun)
  f16*    x16   = (f16*)(ws);
  f16*    wq16  = (f16*)(ws + 102760448);
  f16*    wp16  = (f16*)(ws + 104333312);
  float2* tab   = (float2*)(ws + 104857600);
  f16*    vbuf  = (f16*)(ws + 104873984);
  f16*    attn16 = (f16*)(ws);              // aliases x16 (dead after k_qkv)

  // q,k live inside d_out (205,520,896 bytes); dead before k_proj writes
  f16* qbuf = (f16*)d_out;
  f16* kbuf = (f16*)((char*)d_out + 102760448);
  float* out = (float*)d_out;

  k_prep<<<dim3(25088 + 384 + 128 + 7), dim3(256), 0, stream>>>(
      x, wqkv, wproj, x16, wq16, wp16, tab);
  k_qkv<<<dim3(9408), dim3(256), 0, stream>>>(x16, wq16, tab, qbuf, kbuf, vbuf);
  k_attn<<<dim3(5462), dim3(192), 0, stream>>>(qbuf, kbuf, vbuf, attn16);
  k_proj<<<dim3(3136), dim3(256), 0, stream>>>(attn16, wp16, bias, out);
}